// Round 14
// baseline (1063.496 us; speedup 1.0000x reference)
//
#include <hip/hip_runtime.h>

#define L_NUM 2
#define H_NUM 8
#define D_DIM 64
#define HID_D 512
#define FF_D  2048
#define S_SEQ 256
#define B_NUM 8

typedef unsigned short u16;
typedef unsigned int   u32;
typedef __attribute__((ext_vector_type(8))) short bf16x8;
typedef __attribute__((ext_vector_type(4))) float f32x4;
typedef __attribute__((ext_vector_type(16))) int i32x16;

__device__ __forceinline__ u16 f2bu(float f){
  u32 u = __float_as_uint(f);
  u32 r = (u + 0x7fffu + ((u>>16)&1u)) >> 16;   // RNE to bf16
  return (u16)r;
}

template<int CTL,int RM,int BM>
__device__ __forceinline__ float dpp_add_src(float v){
  return __int_as_float(__builtin_amdgcn_update_dpp(0, __float_as_int(v), CTL, RM, BM, false));
}

// ---------------------------------------------------------------------------
// DPP wave64 sum -> uniform result on all lanes (verified on HW).
// ---------------------------------------------------------------------------
__device__ __forceinline__ float wave_sum(float v){
  float t;
  t = dpp_add_src<0x111,0xf,0xf>(v); v += t;
  t = dpp_add_src<0x112,0xf,0xf>(v); v += t;
  t = dpp_add_src<0x114,0xf,0xf>(v); v += t;
  t = dpp_add_src<0x118,0xf,0xf>(v); v += t;
  t = dpp_add_src<0x142,0xa,0xf>(v); v += t;
  t = dpp_add_src<0x143,0xc,0xf>(v); v += t;
  return __int_as_float(__builtin_amdgcn_readlane(__float_as_int(v), 63));
}

// 4 sums, explicitly interleaved (4 independent chains share the 6 DPP levels).
__device__ __forceinline__ void wave_sum4(float&a,float&b,float&c,float&d){
  float ta,tb,tc,td;
  ta=dpp_add_src<0x111,0xf,0xf>(a); tb=dpp_add_src<0x111,0xf,0xf>(b);
  tc=dpp_add_src<0x111,0xf,0xf>(c); td=dpp_add_src<0x111,0xf,0xf>(d);
  a+=ta; b+=tb; c+=tc; d+=td;
  ta=dpp_add_src<0x112,0xf,0xf>(a); tb=dpp_add_src<0x112,0xf,0xf>(b);
  tc=dpp_add_src<0x112,0xf,0xf>(c); td=dpp_add_src<0x112,0xf,0xf>(d);
  a+=ta; b+=tb; c+=tc; d+=td;
  ta=dpp_add_src<0x114,0xf,0xf>(a); tb=dpp_add_src<0x114,0xf,0xf>(b);
  tc=dpp_add_src<0x114,0xf,0xf>(c); td=dpp_add_src<0x114,0xf,0xf>(d);
  a+=ta; b+=tb; c+=tc; d+=td;
  ta=dpp_add_src<0x118,0xf,0xf>(a); tb=dpp_add_src<0x118,0xf,0xf>(b);
  tc=dpp_add_src<0x118,0xf,0xf>(c); td=dpp_add_src<0x118,0xf,0xf>(d);
  a+=ta; b+=tb; c+=tc; d+=td;
  ta=dpp_add_src<0x142,0xa,0xf>(a); tb=dpp_add_src<0x142,0xa,0xf>(b);
  tc=dpp_add_src<0x142,0xa,0xf>(c); td=dpp_add_src<0x142,0xa,0xf>(d);
  a+=ta; b+=tb; c+=tc; d+=td;
  ta=dpp_add_src<0x143,0xc,0xf>(a); tb=dpp_add_src<0x143,0xc,0xf>(b);
  tc=dpp_add_src<0x143,0xc,0xf>(c); td=dpp_add_src<0x143,0xc,0xf>(d);
  a+=ta; b+=tb; c+=tc; d+=td;
  a=__int_as_float(__builtin_amdgcn_readlane(__float_as_int(a),63));
  b=__int_as_float(__builtin_amdgcn_readlane(__float_as_int(b),63));
  c=__int_as_float(__builtin_amdgcn_readlane(__float_as_int(c),63));
  d=__int_as_float(__builtin_amdgcn_readlane(__float_as_int(d),63));
}

// LDS-only barrier: does NOT drain vmcnt (global ops stay in flight).
__device__ __forceinline__ void lds_barrier(){
  __builtin_amdgcn_sched_barrier(0);
  asm volatile("s_waitcnt lgkmcnt(0)" ::: "memory");
  __builtin_amdgcn_s_barrier();
  __builtin_amdgcn_sched_barrier(0);
}

// Uniform 64-float row -> 64 SGPRs (4x s_load_dwordx16). Pointer MUST be
// provably uniform (SGPR-allocatable). Caller waits lgkmcnt before use.
__device__ __forceinline__ void sload_x64(const float* p,
    i32x16& a, i32x16& b, i32x16& c, i32x16& d){
  asm volatile(
    "s_load_dwordx16 %0, %4, 0x0\n\t"
    "s_load_dwordx16 %1, %4, 0x40\n\t"
    "s_load_dwordx16 %2, %4, 0x80\n\t"
    "s_load_dwordx16 %3, %4, 0xC0"
    : "=&s"(a), "=&s"(b), "=&s"(c), "=&s"(d)
    : "s"((unsigned long long)(__SIZE_TYPE__)p));
}

// ---------------------------------------------------------------------------
// f32 -> bf16 convert, 8 elems/thread.
// ---------------------------------------------------------------------------
__global__ __launch_bounds__(256) void cvt_bf16_k(
    const float* __restrict__ in, u16* __restrict__ out, int n8)
{
  int i = blockIdx.x*256 + threadIdx.x;
  if (i < n8){
    const float4* p = reinterpret_cast<const float4*>(in + (size_t)i*8);
    float4 v0 = p[0], v1 = p[1];
    u16 t[8] = {f2bu(v0.x),f2bu(v0.y),f2bu(v0.z),f2bu(v0.w),
                f2bu(v1.x),f2bu(v1.y),f2bu(v1.z),f2bu(v1.w)};
    *reinterpret_cast<uint4*>(out + (size_t)i*8) = *reinterpret_cast<uint4*>(t);
  }
}

// ---------------------------------------------------------------------------
// Per-head softmax: h (S,B,HID) f32 -> xs (B,H,S,D) f32. One wave per 64-row.
// ---------------------------------------------------------------------------
__global__ __launch_bounds__(256) void softmax_xs_k(
    const float* __restrict__ h, float* __restrict__ xs)
{
  int rid  = blockIdx.x*4 + (threadIdx.x>>6);   // (s*B+b)*H + hd
  int lane = threadIdx.x & 63;
  int hd = rid & (H_NUM-1);
  int sb = rid >> 3;                            // s*B + b
  int b  = sb & (B_NUM-1);
  int s  = sb >> 3;
  float v = h[(size_t)sb*HID_D + hd*D_DIM + lane];
  float m = v;
  #pragma unroll
  for (int off=32; off; off>>=1) m = fmaxf(m, __shfl_xor(m, off));
  float e = __expf(v-m);
  float sum = wave_sum(e);
  xs[(((size_t)(b*H_NUM+hd))*S_SEQ + s)*D_DIM + lane] = e/sum;
}

// ---------------------------------------------------------------------------
// SRWM scan, TWO chains per block on 8 waves (chain=wave>>2, role=wave&3).
// chain hoisted to SGPR via readfirstlane so SMEM x-loads stay scalar.
// ---------------------------------------------------------------------------
__global__ __launch_bounds__(512,1) void scan8_k(
    const float* __restrict__ xs,
    const float* __restrict__ st_y, const float* __restrict__ st_q,
    const float* __restrict__ st_k, const float* __restrict__ st_b,
    const float* __restrict__ p_y,  const float* __restrict__ p_q,
    const float* __restrict__ p_k,  const float* __restrict__ p_b,
    u16* __restrict__ y_out,                    // (S,B,HID) bf16
    float* __restrict__ o_sy, float* __restrict__ o_sq,
    float* __restrict__ o_sk, float* __restrict__ o_sb)
{
  const int wave = threadIdx.x >> 6, lane = threadIdx.x & 63;
  // readfirstlane -> compiler-provable uniform (SGPR) [HK technique]
  const int chain = __builtin_amdgcn_readfirstlane(wave >> 2);   // 0 or 1
  const int role  = wave & 3;
  const int bh = blockIdx.x*2 + chain;
  const int b  = bh >> 3, hh = bh & 7;

  __shared__ __align__(16) float q_s[2][2][64];
  __shared__ __align__(16) float k_s[2][2][64];
  __shared__ float beta_s[2][2][4];

  float W[64];
  float wb0=0.f, wb1=0.f, wb2=0.f, wb3=0.f;
  float xr[8], xn[8];
  float b3_reg=0.f;
  i32x16 xc0, xc1, xc2, xc3;                    // role<3: x row in SGPRs

  const float* xbase = xs + (size_t)bh * (S_SEQ*D_DIM);

  if (role < 3) {
    const float* st = (role==0)? st_y : (role==1)? st_q : st_k;
    const float* pp = (role==0)? p_y  : (role==1)? p_q  : p_k;
    const float4* s4 = reinterpret_cast<const float4*>(st + ((size_t)bh*64 + lane)*64);
    const float4* p4 = reinterpret_cast<const float4*>(pp + ((size_t)hh*64 + lane)*64);
    #pragma unroll
    for (int c=0;c<16;c++){
      float4 a = s4[c], p = p4[c];
      W[c*4+0]=a.x+p.x; W[c*4+1]=a.y+p.y; W[c*4+2]=a.z+p.z; W[c*4+3]=a.w+p.w;
    }
    sload_x64(xbase, xc0, xc1, xc2, xc3);       // x row for t=0
  } else {
    float4 sv = *reinterpret_cast<const float4*>(st_b + ((size_t)bh*64+lane)*4);
    float4 pv = *reinterpret_cast<const float4*>(p_b  + ((size_t)hh*64+lane)*4);
    wb0 = sv.x+pv.x; wb1 = sv.y+pv.y; wb2 = sv.z+pv.z; wb3 = sv.w+pv.w;
    #pragma unroll
    for (int i=0;i<8;i++) xr[i] = xbase[i*D_DIM + lane];
  }
  __syncthreads();

#define MV16(XV, BASE)                                              \
    _Pragma("unroll")                                               \
    for (int e=0;e<16;e+=4){                                        \
      a0 = fmaf(W[(BASE)+e+0], __int_as_float(XV[e+0]), a0);        \
      a1 = fmaf(W[(BASE)+e+1], __int_as_float(XV[e+1]), a1);        \
      a2 = fmaf(W[(BASE)+e+2], __int_as_float(XV[e+2]), a2);        \
      a3 = fmaf(W[(BASE)+e+3], __int_as_float(XV[e+3]), a3);        \
    }

  for (int t0=0; t0<S_SEQ; t0+=8){
    #pragma unroll
    for (int i=0;i<8;i++){
      const int t = t0 + i;
      const int buf = i & 1;
      // ================ phase A ================
      if (role < 3){
        asm volatile("s_waitcnt lgkmcnt(0)" ::: "memory");  // s_load done
        float a0=0.f,a1=0.f,a2=0.f,a3=0.f;
        MV16(xc0, 0)
        MV16(xc1, 16)
        MV16(xc2, 32)
        MV16(xc3, 48)
        float r = (a0+a1)+(a2+a3);
        if (role==0){
          y_out[((size_t)t*B_NUM + b)*HID_D + hh*D_DIM + lane] = f2bu(r);
        } else {
          float e = __expf(r);
          float s = wave_sum(e);
          float val = e * __builtin_amdgcn_rcpf(s);
          (role==1 ? q_s[chain][buf] : k_s[chain][buf])[lane] = val;
        }
      } else {
        if (i == 0){
          #pragma unroll
          for (int ii=0;ii<8;ii++){
            const int tt = (t0+8+ii) & (S_SEQ-1);
            xn[ii] = xbase[tt*D_DIM + lane];
          }
        }
        float xl = xr[i];
        float s0 = wb0*xl, s1 = wb1*xl, s2 = wb2*xl, s3 = wb3*xl;
        wave_sum4(s0,s1,s2,s3);
        float bb0 = __builtin_amdgcn_rcpf(1.f+__expf(-s0));
        float bb1 = __builtin_amdgcn_rcpf(1.f+__expf(-s1));
        float bb2 = __builtin_amdgcn_rcpf(1.f+__expf(-s2));
        b3_reg    = __builtin_amdgcn_rcpf(1.f+__expf(-s3));
        if (lane==0){
          beta_s[chain][buf][0]=bb0; beta_s[chain][buf][1]=bb1;
          beta_s[chain][buf][2]=bb2; beta_s[chain][buf][3]=b3_reg;
        }
      }
      lds_barrier();
      // ================ phase C ================
      if (role < 3){
        { // prefetch next x row into SGPRs (hidden under phase C)
          const int tn = (t+1) & (S_SEQ-1);
          sload_x64(xbase + tn*D_DIM, xc0, xc1, xc2, xc3);
        }
        float bw = beta_s[chain][buf][role];
        float kr[64];
        float a0=0.f,a1=0.f,a2=0.f,a3=0.f;
        #pragma unroll
        for (int j=0;j<16;j++){
          float4 qv = reinterpret_cast<const float4*>(q_s[chain][buf])[j];
          float4 kv = reinterpret_cast<const float4*>(k_s[chain][buf])[j];
          kr[j*4+0]=kv.x; kr[j*4+1]=kv.y; kr[j*4+2]=kv.z; kr[j*4+3]=kv.w;
          a0 = fmaf(W[j*4+0], qv.x-kv.x, a0);
          a1 = fmaf(W[j*4+1], qv.y-kv.y, a1);
          a2 = fmaf(W[j*4+2], qv.z-kv.z, a2);
          a3 = fmaf(W[j*4+3], qv.w-kv.w, a3);
        }
        float rd = (a0+a1)+(a2+a3);
        float cc = bw * rd;
        #pragma unroll
        for (int j=0;j<64;j++)
          W[j] = fmaf(cc, kr[j], W[j]);
      } else {
        float qn = q_s[chain][buf][lane], kn = k_s[chain][buf][lane];
        float dv = qn - kn;
        float d0 = wb0*dv, d1 = wb1*dv, d2 = wb2*dv, d3 = wb3*dv;
        wave_sum4(d0,d1,d2,d3);
        float bk = b3_reg * kn;
        wb0 = fmaf(bk, d0, wb0);
        wb1 = fmaf(bk, d1, wb1);
        wb2 = fmaf(bk, d2, wb2);
        wb3 = fmaf(bk, d3, wb3);
      }
    }
    if (role == 3){
      #pragma unroll
      for (int i=0;i<8;i++) xr[i] = xn[i];
    }
  }
#undef MV16

  if (role < 3){
    const float* pp = (role==0)? p_y : (role==1)? p_q : p_k;
    float* o = ((role==0)? o_sy : (role==1)? o_sq : o_sk) + ((size_t)bh*64 + lane)*64;
    const float4* p4 = reinterpret_cast<const float4*>(pp + ((size_t)hh*64 + lane)*64);
    #pragma unroll
    for (int c=0;c<16;c++){
      float4 p = p4[c];
      float4 w;
      w.x = W[c*4+0]-p.x; w.y = W[c*4+1]-p.y; w.z = W[c*4+2]-p.z; w.w = W[c*4+3]-p.w;
      reinterpret_cast<float4*>(o)[c] = w;
    }
  } else {
    float4 pv = *reinterpret_cast<const float4*>(p_b + ((size_t)hh*64+lane)*4);
    float4 w;
    w.x = wb0-pv.x; w.y = wb1-pv.y; w.z = wb2-pv.z; w.w = wb3-pv.w;
    *reinterpret_cast<float4*>(o_sb + ((size_t)bh*64+lane)*4) = w;
  }
}

// ---------------------------------------------------------------------------
// bf16 MFMA GEMM, bf16 operands: C = A·B^T (+bias)(+Cin)(relu) -> f32 or bf16.
// Tile 128x128, BK=64, 4 waves (2x2 of 64x64), 16x16x32 MFMA.
// ---------------------------------------------------------------------------
template<bool BIAS,bool RELU,bool ADDC,bool OBF>
__global__ __launch_bounds__(256) void mgemm_k(
    const u16* __restrict__ A, const u16* __restrict__ Bw,
    const float* __restrict__ Cin, const float* __restrict__ bias,
    float* __restrict__ Of, u16* __restrict__ Ob,
    int M, int N, int K)
{
  constexpr int BK  = 64;
  constexpr int LDT = 72;                       // u16 row stride (144 B)
  __shared__ __align__(16) u16 As[128][LDT];
  __shared__ __align__(16) u16 Bs[128][LDT];

  const int tid  = threadIdx.x;
  const int wv   = tid >> 6;
  const int lane = tid & 63;
  const int wr   = (wv >> 1) * 64;
  const int wc   = (wv & 1) * 64;
  const int lr   = lane & 15;
  const int lg   = lane >> 4;
  const int m0 = blockIdx.y * 128, n0 = blockIdx.x * 128;

  const int sr = tid >> 1;                      // staging row
  const int sk = (tid & 1) * 32;                // staging k-offset (u16)

  f32x4 acc[4][4] = {};

  for (int kt = 0; kt < K; kt += BK){
    {
      const uint4* src = reinterpret_cast<const uint4*>(A + (size_t)(m0+sr)*K + kt + sk);
      uint4 v0=src[0], v1=src[1], v2=src[2], v3=src[3];
      uint4* dst = reinterpret_cast<uint4*>(&As[sr][sk]);
      dst[0]=v0; dst[1]=v1; dst[2]=v2; dst[3]=v3;
    }
    {
      const uint4* src = reinterpret_cast<const uint4*>(Bw + (size_t)(n0+sr)*K + kt + sk);
      uint4 v0=src[0], v1=src[1], v2=src[2], v3=src[3];
      uint4* dst = reinterpret_cast<uint4*>(&Bs[sr][sk]);
      dst[0]=v0; dst[1]=v1; dst[2]=v2; dst[3]=v3;
    }
    __syncthreads();

    #pragma unroll
    for (int half=0; half<2; ++half){
      bf16x8 af[4], bfb[4];
      #pragma unroll
      for (int i=0;i<4;i++)
        af[i]  = *reinterpret_cast<const bf16x8*>(&As[wr + i*16 + lr][half*32 + lg*8]);
      #pragma unroll
      for (int j=0;j<4;j++)
        bfb[j] = *reinterpret_cast<const bf16x8*>(&Bs[wc + j*16 + lr][half*32 + lg*8]);
      #pragma unroll
      for (int i=0;i<4;i++)
        #pragma unroll
        for (int j=0;j<4;j++)
          acc[i][j] = __builtin_amdgcn_mfma_f32_16x16x32_bf16(af[i], bfb[j], acc[i][j], 0,0,0);
    }
    __syncthreads();
  }

  // epilogue: D mapping col=lane&15, row=(lane>>4)*4+dj  [m89-verified]
  #pragma unroll
  for (int j=0;j<4;j++){
    const int col = n0 + wc + j*16 + lr;
    float bv = 0.f;
    if (BIAS) bv = bias[col];
    #pragma unroll
    for (int i=0;i<4;i++){
      const int rbase = m0 + wr + i*16 + lg*4;
      #pragma unroll
      for (int dj=0;dj<4;dj++){
        const int row = rbase + dj;
        float v = acc[i][j][dj];
        if (BIAS) v += bv;
        if (ADDC) v += Cin[(size_t)row*N + col];
        if (RELU) v = fmaxf(v, 0.f);
        if (OBF) Ob[(size_t)row*N + col] = f2bu(v);
        else     Of[(size_t)row*N + col] = v;
      }
    }
  }
}

// ---------------------------------------------------------------------------
// LayerNorm over HID=512, wave per row, 8 elems/lane. f32 -> bf16.
// ---------------------------------------------------------------------------
__global__ __launch_bounds__(256) void ln_k(
    const float* __restrict__ h, const float* __restrict__ g,
    const float* __restrict__ bb, u16* __restrict__ out)
{
  int row  = blockIdx.x*4 + (threadIdx.x>>6);
  int lane = threadIdx.x & 63;
  const float4* hr = reinterpret_cast<const float4*>(h + (size_t)row*HID_D) + lane*2;
  float4 u = hr[0], v = hr[1];
  float vals[8] = {u.x,u.y,u.z,u.w,v.x,v.y,v.z,v.w};
  float s = 0.f;
  #pragma unroll
  for (int e=0;e<8;e++) s += vals[e];
  s = wave_sum(s);
  float mu = s * (1.f/HID_D);
  float vs = 0.f;
  #pragma unroll
  for (int e=0;e<8;e++){ float d = vals[e]-mu; vs += d*d; }
  vs = wave_sum(vs);
  float rs = rsqrtf(vs*(1.f/HID_D) + 1e-5f);
  const float4* gr = reinterpret_cast<const float4*>(g) + lane*2;
  const float4* br = reinterpret_cast<const float4*>(bb) + lane*2;
  float4 g0 = gr[0], g1 = gr[1], b0 = br[0], b1 = br[1];
  u16 ov[8];
  ov[0] = f2bu((vals[0]-mu)*rs*g0.x + b0.x);
  ov[1] = f2bu((vals[1]-mu)*rs*g0.y + b0.y);
  ov[2] = f2bu((vals[2]-mu)*rs*g0.z + b0.z);
  ov[3] = f2bu((vals[3]-mu)*rs*g0.w + b0.w);
  ov[4] = f2bu((vals[4]-mu)*rs*g1.x + b1.x);
  ov[5] = f2bu((vals[5]-mu)*rs*g1.y + b1.y);
  ov[6] = f2bu((vals[6]-mu)*rs*g1.z + b1.z);
  ov[7] = f2bu((vals[7]-mu)*rs*g1.w + b1.w);
  *reinterpret_cast<uint4*>(out + (size_t)row*HID_D + lane*8) =
      *reinterpret_cast<uint4*>(ov);
}

// ---------------------------------------------------------------------------
extern "C" void kernel_launch(void* const* d_in, const int* in_sizes, int n_in,
                              void* d_out, int out_size, void* d_ws, size_t ws_size,
                              hipStream_t stream)
{
  const float* x    = (const float*)d_in[0];
  const float* sty  = (const float*)d_in[1];
  const float* stq  = (const float*)d_in[2];
  const float* stk  = (const float*)d_in[3];
  const float* stb  = (const float*)d_in[4];
  const float* inW  = (const float*)d_in[5];
  const float* inb  = (const float*)d_in[6];
  const float* py   = (const float*)d_in[7];
  const float* pq   = (const float*)d_in[8];
  const float* pk   = (const float*)d_in[9];
  const float* pb   = (const float*)d_in[10];
  const float* Wo   = (const float*)d_in[11];
  const float* fw1  = (const float*)d_in[12];
  const float* fb1  = (const float*)d_in[13];
  const float* fw2  = (const float*)d_in[14];
  const float* fb2  = (const float*)d_in[15];
  const float* lng  = (const float*)d_in[16];
  const float* lnb  = (const float*)d_in[17];

  char* ws = (char*)d_ws;
  float* h    = (float*)ws;                          // 0..4 MB
  float* xsb  = (float*)(ws + (4<<20));              // 4..8 MB
  u16*   yb   = (u16*)  (ws + (8<<20));              // 8..10 MB (bf16 y)
  u16*   t0   = (u16*)  (ws + (10<<20));             // 10..12 MB (bf16 ln out)
  u16*   t1   = (u16*)  (ws + (12<<20));             // 12..20 MB (bf16 ff mid)
  u16*   xb   = (u16*)  (ws + (20<<20));             // 20..22 MB
  u16*   inWb = (u16*)  (ws + (22<<20));             // 0.5 MB
  u16*   Wob  = (u16*)  (ws + (22<<20) + (512*1024));// 1 MB
  u16*   fw1b = (u16*)  (ws + (23<<20) + (512*1024));// 4 MB
  u16*   fw2b = (u16*)  (ws + (27<<20) + (512*1024));// 4 MB (ends 31.5 MB)

  float* out0 = (float*)d_out;
  const size_t OUT_SZ = (size_t)S_SEQ*B_NUM*HID_D;          // 1048576
  const size_t SYL    = (size_t)B_NUM*H_NUM*D_DIM*D_DIM;    // 262144 per layer
  const size_t SBL    = (size_t)B_NUM*H_NUM*D_DIM*4;        // 16384  per layer
  float* o_sy = out0 + OUT_SZ;
  float* o_sq = o_sy + L_NUM*SYL;
  float* o_sk = o_sq + L_NUM*SYL;
  float* o_sb = o_sk + L_NUM*SYL;

  const int M = S_SEQ*B_NUM;   // 2048

  // one-time bf16 conversions (graph-capture safe, deterministic)
  cvt_bf16_k<<<512, 256,0,stream>>>(x,   xb,   M*512/8);
  cvt_bf16_k<<<128, 256,0,stream>>>(inW, inWb, 512*512/8);
  cvt_bf16_k<<<256, 256,0,stream>>>(Wo,  Wob,  L_NUM*512*512/8);
  cvt_bf16_k<<<1024,256,0,stream>>>(fw1, fw1b, L_NUM*FF_D*HID_D/8);
  cvt_bf16_k<<<1024,256,0,stream>>>(fw2, fw2b, L_NUM*HID_D*FF_D/8);

  // in-projection: h = x @ in_W.T + in_b
  mgemm_k<true,false,false,false><<<dim3(HID_D/128, M/128),256,0,stream>>>(
      xb, inWb, nullptr, inb, h, nullptr, M, HID_D, 512);

  for (int l=0;l<L_NUM;l++){
    softmax_xs_k<<<(S_SEQ*B_NUM*H_NUM)/4, 256, 0, stream>>>(h, xsb);

    scan8_k<<<(B_NUM*H_NUM)/2, 512, 0, stream>>>(xsb,
        sty + (size_t)l*SYL, stq + (size_t)l*SYL, stk + (size_t)l*SYL, stb + (size_t)l*SBL,
        py + (size_t)l*H_NUM*D_DIM*D_DIM, pq + (size_t)l*H_NUM*D_DIM*D_DIM,
        pk + (size_t)l*H_NUM*D_DIM*D_DIM, pb + (size_t)l*H_NUM*D_DIM*4,
        yb,
        o_sy + l*SYL, o_sq + l*SYL, o_sk + l*SYL, o_sb + l*SBL);

    // h += y @ Wo.T
    mgemm_k<false,false,true,false><<<dim3(HID_D/128, M/128),256,0,stream>>>(
        yb, Wob + (size_t)l*HID_D*HID_D, h, nullptr, h, nullptr, M, HID_D, HID_D);

    ln_k<<<M/4,256,0,stream>>>(h, lng + l*HID_D, lnb + l*HID_D, t0);

    // t1 = relu(ln @ ff_W1.T + b1)  -> bf16
    mgemm_k<true,true,false,true><<<dim3(FF_D/128, M/128),256,0,stream>>>(
        t0, fw1b + (size_t)l*FF_D*HID_D, nullptr, fb1 + l*FF_D, nullptr, t1, M, FF_D, HID_D);

    // h(+out) = h + t1 @ ff_W2.T + b2   (last layer writes d_out directly)
    float* dst = (l==L_NUM-1) ? out0 : h;
    mgemm_k<true,false,true,false><<<dim3(HID_D/128, M/128),256,0,stream>>>(
        t1, fw2b + (size_t)l*HID_D*FF_D, h, fb2 + l*HID_D, dst, nullptr, M, HID_D, FF_D);
  }
}

// Round 15
// 734.793 us; speedup vs baseline: 1.4473x; 1.4473x over previous
//
#include <hip/hip_runtime.h>

#define L_NUM 2
#define H_NUM 8
#define D_DIM 64
#define HID_D 512
#define FF_D  2048
#define S_SEQ 256
#define B_NUM 8

typedef unsigned short u16;
typedef unsigned int   u32;
typedef __attribute__((ext_vector_type(8))) short bf16x8;
typedef __attribute__((ext_vector_type(4))) float f32x4;
typedef __attribute__((ext_vector_type(16))) int i32x16;

__device__ __forceinline__ u16 f2bu(float f){
  u32 u = __float_as_uint(f);
  u32 r = (u + 0x7fffu + ((u>>16)&1u)) >> 16;   // RNE to bf16
  return (u16)r;
}

template<int CTL,int RM,int BM>
__device__ __forceinline__ float dpp_add_src(float v){
  return __int_as_float(__builtin_amdgcn_update_dpp(0, __float_as_int(v), CTL, RM, BM, false));
}

// ---------------------------------------------------------------------------
// DPP wave64 sum -> uniform result on all lanes (verified on HW).
// ---------------------------------------------------------------------------
__device__ __forceinline__ float wave_sum(float v){
  float t;
  t = dpp_add_src<0x111,0xf,0xf>(v); v += t;
  t = dpp_add_src<0x112,0xf,0xf>(v); v += t;
  t = dpp_add_src<0x114,0xf,0xf>(v); v += t;
  t = dpp_add_src<0x118,0xf,0xf>(v); v += t;
  t = dpp_add_src<0x142,0xa,0xf>(v); v += t;
  t = dpp_add_src<0x143,0xc,0xf>(v); v += t;
  return __int_as_float(__builtin_amdgcn_readlane(__float_as_int(v), 63));
}

// 4 sums, explicitly interleaved (4 independent chains share the 6 DPP levels).
__device__ __forceinline__ void wave_sum4(float&a,float&b,float&c,float&d){
  float ta,tb,tc,td;
  ta=dpp_add_src<0x111,0xf,0xf>(a); tb=dpp_add_src<0x111,0xf,0xf>(b);
  tc=dpp_add_src<0x111,0xf,0xf>(c); td=dpp_add_src<0x111,0xf,0xf>(d);
  a+=ta; b+=tb; c+=tc; d+=td;
  ta=dpp_add_src<0x112,0xf,0xf>(a); tb=dpp_add_src<0x112,0xf,0xf>(b);
  tc=dpp_add_src<0x112,0xf,0xf>(c); td=dpp_add_src<0x112,0xf,0xf>(d);
  a+=ta; b+=tb; c+=tc; d+=td;
  ta=dpp_add_src<0x114,0xf,0xf>(a); tb=dpp_add_src<0x114,0xf,0xf>(b);
  tc=dpp_add_src<0x114,0xf,0xf>(c); td=dpp_add_src<0x114,0xf,0xf>(d);
  a+=ta; b+=tb; c+=tc; d+=td;
  ta=dpp_add_src<0x118,0xf,0xf>(a); tb=dpp_add_src<0x118,0xf,0xf>(b);
  tc=dpp_add_src<0x118,0xf,0xf>(c); td=dpp_add_src<0x118,0xf,0xf>(d);
  a+=ta; b+=tb; c+=tc; d+=td;
  ta=dpp_add_src<0x142,0xa,0xf>(a); tb=dpp_add_src<0x142,0xa,0xf>(b);
  tc=dpp_add_src<0x142,0xa,0xf>(c); td=dpp_add_src<0x142,0xa,0xf>(d);
  a+=ta; b+=tb; c+=tc; d+=td;
  ta=dpp_add_src<0x143,0xc,0xf>(a); tb=dpp_add_src<0x143,0xc,0xf>(b);
  tc=dpp_add_src<0x143,0xc,0xf>(c); td=dpp_add_src<0x143,0xc,0xf>(d);
  a+=ta; b+=tb; c+=tc; d+=td;
  a=__int_as_float(__builtin_amdgcn_readlane(__float_as_int(a),63));
  b=__int_as_float(__builtin_amdgcn_readlane(__float_as_int(b),63));
  c=__int_as_float(__builtin_amdgcn_readlane(__float_as_int(c),63));
  d=__int_as_float(__builtin_amdgcn_readlane(__float_as_int(d),63));
}

// LDS-only barrier: does NOT drain vmcnt (global ops stay in flight).
__device__ __forceinline__ void lds_barrier(){
  __builtin_amdgcn_sched_barrier(0);
  asm volatile("s_waitcnt lgkmcnt(0)" ::: "memory");
  __builtin_amdgcn_s_barrier();
  __builtin_amdgcn_sched_barrier(0);
}

// Uniform 64-float row -> 64 SGPRs (4x s_load_dwordx16). Pointer MUST be
// provably uniform (SGPR-allocatable). Caller waits lgkmcnt before use.
__device__ __forceinline__ void sload_x64(const float* p,
    i32x16& a, i32x16& b, i32x16& c, i32x16& d){
  asm volatile(
    "s_load_dwordx16 %0, %4, 0x0\n\t"
    "s_load_dwordx16 %1, %4, 0x40\n\t"
    "s_load_dwordx16 %2, %4, 0x80\n\t"
    "s_load_dwordx16 %3, %4, 0xC0"
    : "=&s"(a), "=&s"(b), "=&s"(c), "=&s"(d)
    : "s"((unsigned long long)(__SIZE_TYPE__)p));
}

// ---------------------------------------------------------------------------
// f32 -> bf16 convert, 8 elems/thread.
// ---------------------------------------------------------------------------
__global__ __launch_bounds__(256) void cvt_bf16_k(
    const float* __restrict__ in, u16* __restrict__ out, int n8)
{
  int i = blockIdx.x*256 + threadIdx.x;
  if (i < n8){
    const float4* p = reinterpret_cast<const float4*>(in + (size_t)i*8);
    float4 v0 = p[0], v1 = p[1];
    u16 t[8] = {f2bu(v0.x),f2bu(v0.y),f2bu(v0.z),f2bu(v0.w),
                f2bu(v1.x),f2bu(v1.y),f2bu(v1.z),f2bu(v1.w)};
    *reinterpret_cast<uint4*>(out + (size_t)i*8) = *reinterpret_cast<uint4*>(t);
  }
}

// ---------------------------------------------------------------------------
// Per-head softmax: h (S,B,HID) f32 -> xs (B,H,S,D) f32. One wave per 64-row.
// ---------------------------------------------------------------------------
__global__ __launch_bounds__(256) void softmax_xs_k(
    const float* __restrict__ h, float* __restrict__ xs)
{
  int rid  = blockIdx.x*4 + (threadIdx.x>>6);   // (s*B+b)*H + hd
  int lane = threadIdx.x & 63;
  int hd = rid & (H_NUM-1);
  int sb = rid >> 3;                            // s*B + b
  int b  = sb & (B_NUM-1);
  int s  = sb >> 3;
  float v = h[(size_t)sb*HID_D + hd*D_DIM + lane];
  float m = v;
  #pragma unroll
  for (int off=32; off; off>>=1) m = fmaxf(m, __shfl_xor(m, off));
  float e = __expf(v-m);
  float sum = wave_sum(e);
  xs[(((size_t)(b*H_NUM+hd))*S_SEQ + s)*D_DIM + lane] = e/sum;
}

// ---------------------------------------------------------------------------
// SRWM scan, 4 waves per (b,h). x broadcast via SGPRs (s_load) for waves 0-2
// -> x never touches the LDS pipe. q/k/beta in dbuf LDS; 1 barrier/step.
// (R12-verified: 292 us)
// ---------------------------------------------------------------------------
__global__ __launch_bounds__(256,1) void scan4_k(
    const float* __restrict__ xs,
    const float* __restrict__ st_y, const float* __restrict__ st_q,
    const float* __restrict__ st_k, const float* __restrict__ st_b,
    const float* __restrict__ p_y,  const float* __restrict__ p_q,
    const float* __restrict__ p_k,  const float* __restrict__ p_b,
    u16* __restrict__ y_out,                    // (S,B,HID) bf16
    float* __restrict__ o_sy, float* __restrict__ o_sq,
    float* __restrict__ o_sk, float* __restrict__ o_sb)
{
  const int bh = blockIdx.x;
  const int b  = bh >> 3, hh = bh & 7;
  const int wave = threadIdx.x >> 6, lane = threadIdx.x & 63;

  __shared__ __align__(16) float q_s[2][64];
  __shared__ __align__(16) float k_s[2][64];
  __shared__ float beta_s[2][4];

  float W[64];
  float wb0=0.f, wb1=0.f, wb2=0.f, wb3=0.f;
  float xr[8], xn[8];
  float b3_reg=0.f;
  i32x16 xc0, xc1, xc2, xc3;                    // wave<3: x row in SGPRs

  const float* xbase = xs + (size_t)bh * (S_SEQ*D_DIM);

  if (wave < 3) {
    const float* st = (wave==0)? st_y : (wave==1)? st_q : st_k;
    const float* pp = (wave==0)? p_y  : (wave==1)? p_q  : p_k;
    const float4* s4 = reinterpret_cast<const float4*>(st + ((size_t)bh*64 + lane)*64);
    const float4* p4 = reinterpret_cast<const float4*>(pp + ((size_t)hh*64 + lane)*64);
    #pragma unroll
    for (int c=0;c<16;c++){
      float4 a = s4[c], p = p4[c];
      W[c*4+0]=a.x+p.x; W[c*4+1]=a.y+p.y; W[c*4+2]=a.z+p.z; W[c*4+3]=a.w+p.w;
    }
    sload_x64(xbase, xc0, xc1, xc2, xc3);       // x row for t=0
  } else {
    float4 sv = *reinterpret_cast<const float4*>(st_b + ((size_t)bh*64+lane)*4);
    float4 pv = *reinterpret_cast<const float4*>(p_b  + ((size_t)hh*64+lane)*4);
    wb0 = sv.x+pv.x; wb1 = sv.y+pv.y; wb2 = sv.z+pv.z; wb3 = sv.w+pv.w;
    #pragma unroll
    for (int i=0;i<8;i++) xr[i] = xbase[i*D_DIM + lane];
  }
  __syncthreads();

#define MV16(XV, BASE)                                              \
    _Pragma("unroll")                                               \
    for (int e=0;e<16;e+=4){                                        \
      a0 = fmaf(W[(BASE)+e+0], __int_as_float(XV[e+0]), a0);        \
      a1 = fmaf(W[(BASE)+e+1], __int_as_float(XV[e+1]), a1);        \
      a2 = fmaf(W[(BASE)+e+2], __int_as_float(XV[e+2]), a2);        \
      a3 = fmaf(W[(BASE)+e+3], __int_as_float(XV[e+3]), a3);        \
    }

  for (int t0=0; t0<S_SEQ; t0+=8){
    #pragma unroll
    for (int i=0;i<8;i++){
      const int t = t0 + i;
      const int buf = i & 1;
      // ================ phase A ================
      if (wave < 3){
        asm volatile("s_waitcnt lgkmcnt(0)" ::: "memory");  // s_load done
        float a0=0.f,a1=0.f,a2=0.f,a3=0.f;
        MV16(xc0, 0)
        MV16(xc1, 16)
        MV16(xc2, 32)
        MV16(xc3, 48)
        float r = (a0+a1)+(a2+a3);
        if (wave==0){
          y_out[((size_t)t*B_NUM + b)*HID_D + hh*D_DIM + lane] = f2bu(r);
        } else {
          float e = __expf(r);
          float s = wave_sum(e);
          float val = e * __builtin_amdgcn_rcpf(s);
          (wave==1 ? q_s[buf] : k_s[buf])[lane] = val;
        }
      } else {
        if (i == 0){
          #pragma unroll
          for (int ii=0;ii<8;ii++){
            const int tt = (t0+8+ii) & (S_SEQ-1);
            xn[ii] = xbase[tt*D_DIM + lane];
          }
        }
        float xl = xr[i];
        float s0 = wb0*xl, s1 = wb1*xl, s2 = wb2*xl, s3 = wb3*xl;
        wave_sum4(s0,s1,s2,s3);
        float bb0 = __builtin_amdgcn_rcpf(1.f+__expf(-s0));
        float bb1 = __builtin_amdgcn_rcpf(1.f+__expf(-s1));
        float bb2 = __builtin_amdgcn_rcpf(1.f+__expf(-s2));
        b3_reg    = __builtin_amdgcn_rcpf(1.f+__expf(-s3));
        if (lane==0){
          beta_s[buf][0]=bb0; beta_s[buf][1]=bb1; beta_s[buf][2]=bb2;
          beta_s[buf][3]=b3_reg;
        }
      }
      lds_barrier();
      // ================ phase C ================
      if (wave < 3){
        { // prefetch next x row into SGPRs (hidden under phase C)
          const int tn = (t+1) & (S_SEQ-1);
          sload_x64(xbase + tn*D_DIM, xc0, xc1, xc2, xc3);
        }
        float bw = beta_s[buf][wave];
        float kr[64];
        float a0=0.f,a1=0.f,a2=0.f,a3=0.f;
        #pragma unroll
        for (int j=0;j<16;j++){
          float4 qv = reinterpret_cast<const float4*>(q_s[buf])[j];
          float4 kv = reinterpret_cast<const float4*>(k_s[buf])[j];
          kr[j*4+0]=kv.x; kr[j*4+1]=kv.y; kr[j*4+2]=kv.z; kr[j*4+3]=kv.w;
          a0 = fmaf(W[j*4+0], qv.x-kv.x, a0);
          a1 = fmaf(W[j*4+1], qv.y-kv.y, a1);
          a2 = fmaf(W[j*4+2], qv.z-kv.z, a2);
          a3 = fmaf(W[j*4+3], qv.w-kv.w, a3);
        }
        float rd = (a0+a1)+(a2+a3);
        float cc = bw * rd;
        #pragma unroll
        for (int j=0;j<64;j++)
          W[j] = fmaf(cc, kr[j], W[j]);
      } else {
        float qn = q_s[buf][lane], kn = k_s[buf][lane];
        float dv = qn - kn;
        float d0 = wb0*dv, d1 = wb1*dv, d2 = wb2*dv, d3 = wb3*dv;
        wave_sum4(d0,d1,d2,d3);
        float bk = b3_reg * kn;
        wb0 = fmaf(bk, d0, wb0);
        wb1 = fmaf(bk, d1, wb1);
        wb2 = fmaf(bk, d2, wb2);
        wb3 = fmaf(bk, d3, wb3);
      }
    }
    if (wave == 3){
      #pragma unroll
      for (int i=0;i<8;i++) xr[i] = xn[i];
    }
  }
#undef MV16

  if (wave < 3){
    const float* pp = (wave==0)? p_y : (wave==1)? p_q : p_k;
    float* o = ((wave==0)? o_sy : (wave==1)? o_sq : o_sk) + ((size_t)bh*64 + lane)*64;
    const float4* p4 = reinterpret_cast<const float4*>(pp + ((size_t)hh*64 + lane)*64);
    #pragma unroll
    for (int c=0;c<16;c++){
      float4 p = p4[c];
      float4 w;
      w.x = W[c*4+0]-p.x; w.y = W[c*4+1]-p.y; w.z = W[c*4+2]-p.z; w.w = W[c*4+3]-p.w;
      reinterpret_cast<float4*>(o)[c] = w;
    }
  } else {
    float4 pv = *reinterpret_cast<const float4*>(p_b + ((size_t)hh*64+lane)*4);
    float4 w;
    w.x = wb0-pv.x; w.y = wb1-pv.y; w.z = wb2-pv.z; w.w = wb3-pv.w;
    *reinterpret_cast<float4*>(o_sb + ((size_t)bh*64+lane)*4) = w;
  }
}

// ---------------------------------------------------------------------------
// bf16 MFMA GEMM, bf16 operands: C = A·B^T (+bias)(+Cin)(relu) -> f32 or bf16.
// Tile BMxBN (templated), BK=64, 4 waves (2x2 of BM/2 x BN/2), 16x16x32 MFMA.
// 64x64 tile used for N=512 GEMMs to fill all 256 CUs (grid 8x32).
// ---------------------------------------------------------------------------
template<int BM,int BN,bool BIAS,bool RELU,bool ADDC,bool OBF>
__global__ __launch_bounds__(256) void mgemm_k(
    const u16* __restrict__ A, const u16* __restrict__ Bw,
    const float* __restrict__ Cin, const float* __restrict__ bias,
    float* __restrict__ Of, u16* __restrict__ Ob,
    int M, int N, int K)
{
  constexpr int BK  = 64;
  constexpr int LDT = 72;                       // u16 row stride (144 B)
  constexpr int WM  = BM/2, WN = BN/2;
  constexpr int FI  = WM/16, FJ = WN/16;
  __shared__ __align__(16) u16 As[BM][LDT];
  __shared__ __align__(16) u16 Bs[BN][LDT];

  const int tid  = threadIdx.x;
  const int wv   = tid >> 6;
  const int lane = tid & 63;
  const int wr   = (wv >> 1) * WM;
  const int wc   = (wv & 1) * WN;
  const int lr   = lane & 15;
  const int lg   = lane >> 4;
  const int m0 = blockIdx.y * BM, n0 = blockIdx.x * BN;

  // staging: TPR threads/row, CH u16 per thread (CH/8 uint4 chunks)
  constexpr int TPRA = 256/BM, CHA = BK/TPRA;
  constexpr int TPRB = 256/BN, CHB = BK/TPRB;
  const int srA = tid / TPRA, skA = (tid % TPRA) * CHA;
  const int srB = tid / TPRB, skB = (tid % TPRB) * CHB;

  f32x4 acc[FI][FJ] = {};

  for (int kt = 0; kt < K; kt += BK){
    {
      const uint4* src = reinterpret_cast<const uint4*>(A + (size_t)(m0+srA)*K + kt + skA);
      uint4* dst = reinterpret_cast<uint4*>(&As[srA][skA]);
      #pragma unroll
      for (int c=0;c<CHA/8;c++) dst[c] = src[c];
    }
    {
      const uint4* src = reinterpret_cast<const uint4*>(Bw + (size_t)(n0+srB)*K + kt + skB);
      uint4* dst = reinterpret_cast<uint4*>(&Bs[srB][skB]);
      #pragma unroll
      for (int c=0;c<CHB/8;c++) dst[c] = src[c];
    }
    __syncthreads();

    #pragma unroll
    for (int half=0; half<2; ++half){
      bf16x8 af[FI], bfb[FJ];
      #pragma unroll
      for (int i=0;i<FI;i++)
        af[i]  = *reinterpret_cast<const bf16x8*>(&As[wr + i*16 + lr][half*32 + lg*8]);
      #pragma unroll
      for (int j=0;j<FJ;j++)
        bfb[j] = *reinterpret_cast<const bf16x8*>(&Bs[wc + j*16 + lr][half*32 + lg*8]);
      #pragma unroll
      for (int i=0;i<FI;i++)
        #pragma unroll
        for (int j=0;j<FJ;j++)
          acc[i][j] = __builtin_amdgcn_mfma_f32_16x16x32_bf16(af[i], bfb[j], acc[i][j], 0,0,0);
    }
    __syncthreads();
  }

  // epilogue: D mapping col=lane&15, row=(lane>>4)*4+dj  [m89-verified]
  #pragma unroll
  for (int j=0;j<FJ;j++){
    const int col = n0 + wc + j*16 + lr;
    float bv = 0.f;
    if (BIAS) bv = bias[col];
    #pragma unroll
    for (int i=0;i<FI;i++){
      const int rbase = m0 + wr + i*16 + lg*4;
      #pragma unroll
      for (int dj=0;dj<4;dj++){
        const int row = rbase + dj;
        float v = acc[i][j][dj];
        if (BIAS) v += bv;
        if (ADDC) v += Cin[(size_t)row*N + col];
        if (RELU) v = fmaxf(v, 0.f);
        if (OBF) Ob[(size_t)row*N + col] = f2bu(v);
        else     Of[(size_t)row*N + col] = v;
      }
    }
  }
}

// ---------------------------------------------------------------------------
// LayerNorm over HID=512, wave per row, 8 elems/lane. f32 -> bf16.
// ---------------------------------------------------------------------------
__global__ __launch_bounds__(256) void ln_k(
    const float* __restrict__ h, const float* __restrict__ g,
    const float* __restrict__ bb, u16* __restrict__ out)
{
  int row  = blockIdx.x*4 + (threadIdx.x>>6);
  int lane = threadIdx.x & 63;
  const float4* hr = reinterpret_cast<const float4*>(h + (size_t)row*HID_D) + lane*2;
  float4 u = hr[0], v = hr[1];
  float vals[8] = {u.x,u.y,u.z,u.w,v.x,v.y,v.z,v.w};
  float s = 0.f;
  #pragma unroll
  for (int e=0;e<8;e++) s += vals[e];
  s = wave_sum(s);
  float mu = s * (1.f/HID_D);
  float vs = 0.f;
  #pragma unroll
  for (int e=0;e<8;e++){ float d = vals[e]-mu; vs += d*d; }
  vs = wave_sum(vs);
  float rs = rsqrtf(vs*(1.f/HID_D) + 1e-5f);
  const float4* gr = reinterpret_cast<const float4*>(g) + lane*2;
  const float4* br = reinterpret_cast<const float4*>(bb) + lane*2;
  float4 g0 = gr[0], g1 = gr[1], b0 = br[0], b1 = br[1];
  u16 ov[8];
  ov[0] = f2bu((vals[0]-mu)*rs*g0.x + b0.x);
  ov[1] = f2bu((vals[1]-mu)*rs*g0.y + b0.y);
  ov[2] = f2bu((vals[2]-mu)*rs*g0.z + b0.z);
  ov[3] = f2bu((vals[3]-mu)*rs*g0.w + b0.w);
  ov[4] = f2bu((vals[4]-mu)*rs*g1.x + b1.x);
  ov[5] = f2bu((vals[5]-mu)*rs*g1.y + b1.y);
  ov[6] = f2bu((vals[6]-mu)*rs*g1.z + b1.z);
  ov[7] = f2bu((vals[7]-mu)*rs*g1.w + b1.w);
  *reinterpret_cast<uint4*>(out + (size_t)row*HID_D + lane*8) =
      *reinterpret_cast<uint4*>(ov);
}

// ---------------------------------------------------------------------------
extern "C" void kernel_launch(void* const* d_in, const int* in_sizes, int n_in,
                              void* d_out, int out_size, void* d_ws, size_t ws_size,
                              hipStream_t stream)
{
  const float* x    = (const float*)d_in[0];
  const float* sty  = (const float*)d_in[1];
  const float* stq  = (const float*)d_in[2];
  const float* stk  = (const float*)d_in[3];
  const float* stb  = (const float*)d_in[4];
  const float* inW  = (const float*)d_in[5];
  const float* inb  = (const float*)d_in[6];
  const float* py   = (const float*)d_in[7];
  const float* pq   = (const float*)d_in[8];
  const float* pk   = (const float*)d_in[9];
  const float* pb   = (const float*)d_in[10];
  const float* Wo   = (const float*)d_in[11];
  const float* fw1  = (const float*)d_in[12];
  const float* fb1  = (const float*)d_in[13];
  const float* fw2  = (const float*)d_in[14];
  const float* fb2  = (const float*)d_in[15];
  const float* lng  = (const float*)d_in[16];
  const float* lnb  = (const float*)d_in[17];

  char* ws = (char*)d_ws;
  float* h    = (float*)ws;                          // 0..4 MB
  float* xsb  = (float*)(ws + (4<<20));              // 4..8 MB
  u16*   yb   = (u16*)  (ws + (8<<20));              // 8..10 MB (bf16 y)
  u16*   t0   = (u16*)  (ws + (10<<20));             // 10..12 MB (bf16 ln out)
  u16*   t1   = (u16*)  (ws + (12<<20));             // 12..20 MB (bf16 ff mid)
  u16*   xb   = (u16*)  (ws + (20<<20));             // 20..22 MB
  u16*   inWb = (u16*)  (ws + (22<<20));             // 0.5 MB
  u16*   Wob  = (u16*)  (ws + (22<<20) + (512*1024));// 1 MB
  u16*   fw1b = (u16*)  (ws + (23<<20) + (512*1024));// 4 MB
  u16*   fw2b = (u16*)  (ws + (27<<20) + (512*1024));// 4 MB (ends 31.5 MB)

  float* out0 = (float*)d_out;
  const size_t OUT_SZ = (size_t)S_SEQ*B_NUM*HID_D;          // 1048576
  const size_t SYL    = (size_t)B_NUM*H_NUM*D_DIM*D_DIM;    // 262144 per layer
  const size_t SBL    = (size_t)B_NUM*H_NUM*D_DIM*4;        // 16384  per layer
  float* o_sy = out0 + OUT_SZ;
  float* o_sq = o_sy + L_NUM*SYL;
  float* o_sk = o_sq + L_NUM*SYL;
  float* o_sb = o_sk + L_NUM*SYL;

  const int M = S_SEQ*B_NUM;   // 2048

  // one-time bf16 conversions (graph-capture safe, deterministic)
  cvt_bf16_k<<<512, 256,0,stream>>>(x,   xb,   M*512/8);
  cvt_bf16_k<<<128, 256,0,stream>>>(inW, inWb, 512*512/8);
  cvt_bf16_k<<<256, 256,0,stream>>>(Wo,  Wob,  L_NUM*512*512/8);
  cvt_bf16_k<<<1024,256,0,stream>>>(fw1, fw1b, L_NUM*FF_D*HID_D/8);
  cvt_bf16_k<<<1024,256,0,stream>>>(fw2, fw2b, L_NUM*HID_D*FF_D/8);

  // in-projection: h = x @ in_W.T + in_b   (64x64 tile -> 256 blocks)
  mgemm_k<64,64,true,false,false,false><<<dim3(HID_D/64, M/64),256,0,stream>>>(
      xb, inWb, nullptr, inb, h, nullptr, M, HID_D, 512);

  for (int l=0;l<L_NUM;l++){
    softmax_xs_k<<<(S_SEQ*B_NUM*H_NUM)/4, 256, 0, stream>>>(h, xsb);

    scan4_k<<<B_NUM*H_NUM, 256, 0, stream>>>(xsb,
        sty + (size_t)l*SYL, stq + (size_t)l*SYL, stk + (size_t)l*SYL, stb + (size_t)l*SBL,
        py + (size_t)l*H_NUM*D_DIM*D_DIM, pq + (size_t)l*H_NUM*D_DIM*D_DIM,
        pk + (size_t)l*H_NUM*D_DIM*D_DIM, pb + (size_t)l*H_NUM*D_DIM*4,
        yb,
        o_sy + l*SYL, o_sq + l*SYL, o_sk + l*SYL, o_sb + l*SBL);

    // h += y @ Wo.T   (64x64 tile -> 256 blocks)
    mgemm_k<64,64,false,false,true,false><<<dim3(HID_D/64, M/64),256,0,stream>>>(
        yb, Wob + (size_t)l*HID_D*HID_D, h, nullptr, h, nullptr, M, HID_D, HID_D);

    ln_k<<<M/4,256,0,stream>>>(h, lng + l*HID_D, lnb + l*HID_D, t0);

    // t1 = relu(ln @ ff_W1.T + b1)  -> bf16  (128x128 tile, 256 blocks)
    mgemm_k<128,128,true,true,false,true><<<dim3(FF_D/128, M/128),256,0,stream>>>(
        t0, fw1b + (size_t)l*FF_D*HID_D, nullptr, fb1 + l*FF_D, nullptr, t1, M, FF_D, HID_D);

    // h(+out) = h + t1 @ ff_W2.T + b2   (64x64 tile -> 256 blocks)
    float* dst = (l==L_NUM-1) ? out0 : h;
    mgemm_k<64,64,true,false,true,false><<<dim3(HID_D/64, M/64),256,0,stream>>>(
        t1, fw2b + (size_t)l*HID_D*FF_D, h, fb2 + l*HID_D, dst, nullptr, M, HID_D, FF_D);
  }
}

// Round 18
// 725.710 us; speedup vs baseline: 1.4655x; 1.0125x over previous
//
#include <hip/hip_runtime.h>

#define L_NUM 2
#define H_NUM 8
#define D_DIM 64
#define HID_D 512
#define FF_D  2048
#define S_SEQ 256
#define B_NUM 8

typedef unsigned short u16;
typedef unsigned int   u32;
typedef __attribute__((ext_vector_type(8))) short bf16x8;
typedef __attribute__((ext_vector_type(4))) float f32x4;
typedef __attribute__((ext_vector_type(16))) int i32x16;

__device__ __forceinline__ u16 f2bu(float f){
  u32 u = __float_as_uint(f);
  u32 r = (u + 0x7fffu + ((u>>16)&1u)) >> 16;   // RNE to bf16
  return (u16)r;
}

template<int CTL,int RM,int BM>
__device__ __forceinline__ float dpp_add_src(float v){
  return __int_as_float(__builtin_amdgcn_update_dpp(0, __float_as_int(v), CTL, RM, BM, false));
}

__device__ __forceinline__ float rlane(float v, int l){
  return __int_as_float(__builtin_amdgcn_readlane(__float_as_int(v), l));
}

// ---------------------------------------------------------------------------
// Wave64 sum, shallow: 4 DPP row_shr levels (exact row sums land in lanes
// 15/31/47/63; 0-identity fill) + 4 parallel readlanes + 3 adds. Exact.
// ---------------------------------------------------------------------------
__device__ __forceinline__ float wave_sum(float v){
  float t;
  t = dpp_add_src<0x111,0xf,0xf>(v); v += t;
  t = dpp_add_src<0x112,0xf,0xf>(v); v += t;
  t = dpp_add_src<0x114,0xf,0xf>(v); v += t;
  t = dpp_add_src<0x118,0xf,0xf>(v); v += t;
  return (rlane(v,15)+rlane(v,31))+(rlane(v,47)+rlane(v,63));
}

// 4 interleaved sums (independent chains share the 4 DPP levels).
__device__ __forceinline__ void wave_sum4(float&a,float&b,float&c,float&d){
  float ta,tb,tc,td;
  ta=dpp_add_src<0x111,0xf,0xf>(a); tb=dpp_add_src<0x111,0xf,0xf>(b);
  tc=dpp_add_src<0x111,0xf,0xf>(c); td=dpp_add_src<0x111,0xf,0xf>(d);
  a+=ta; b+=tb; c+=tc; d+=td;
  ta=dpp_add_src<0x112,0xf,0xf>(a); tb=dpp_add_src<0x112,0xf,0xf>(b);
  tc=dpp_add_src<0x112,0xf,0xf>(c); td=dpp_add_src<0x112,0xf,0xf>(d);
  a+=ta; b+=tb; c+=tc; d+=td;
  ta=dpp_add_src<0x114,0xf,0xf>(a); tb=dpp_add_src<0x114,0xf,0xf>(b);
  tc=dpp_add_src<0x114,0xf,0xf>(c); td=dpp_add_src<0x114,0xf,0xf>(d);
  a+=ta; b+=tb; c+=tc; d+=td;
  ta=dpp_add_src<0x118,0xf,0xf>(a); tb=dpp_add_src<0x118,0xf,0xf>(b);
  tc=dpp_add_src<0x118,0xf,0xf>(c); td=dpp_add_src<0x118,0xf,0xf>(d);
  a+=ta; b+=tb; c+=tc; d+=td;
  a = (rlane(a,15)+rlane(a,31))+(rlane(a,47)+rlane(a,63));
  b = (rlane(b,15)+rlane(b,31))+(rlane(b,47)+rlane(b,63));
  c = (rlane(c,15)+rlane(c,31))+(rlane(c,47)+rlane(c,63));
  d = (rlane(d,15)+rlane(d,31))+(rlane(d,47)+rlane(d,63));
}

// LDS-only barrier: does NOT drain vmcnt (global ops stay in flight).
__device__ __forceinline__ void lds_barrier(){
  __builtin_amdgcn_sched_barrier(0);
  asm volatile("s_waitcnt lgkmcnt(0)" ::: "memory");
  __builtin_amdgcn_s_barrier();
  __builtin_amdgcn_sched_barrier(0);
}

// Uniform 64-float row -> 64 SGPRs (4x s_load_dwordx16). Pointer MUST be
// provably uniform (SGPR-allocatable). Caller waits lgkmcnt before use.
// NOTE: only safe for data produced by a PRIOR kernel (K$ invalidated at
// dispatch start) — never for data stored by this same dispatch.
__device__ __forceinline__ void sload_x64(const float* p,
    i32x16& a, i32x16& b, i32x16& c, i32x16& d){
  asm volatile(
    "s_load_dwordx16 %0, %4, 0x0\n\t"
    "s_load_dwordx16 %1, %4, 0x40\n\t"
    "s_load_dwordx16 %2, %4, 0x80\n\t"
    "s_load_dwordx16 %3, %4, 0xC0"
    : "=&s"(a), "=&s"(b), "=&s"(c), "=&s"(d)
    : "s"((unsigned long long)(__SIZE_TYPE__)p));
}

// ---------------------------------------------------------------------------
// f32 -> bf16 convert, 8 elems/thread.
// ---------------------------------------------------------------------------
__global__ __launch_bounds__(256) void cvt_bf16_k(
    const float* __restrict__ in, u16* __restrict__ out, int n8)
{
  int i = blockIdx.x*256 + threadIdx.x;
  if (i < n8){
    const float4* p = reinterpret_cast<const float4*>(in + (size_t)i*8);
    float4 v0 = p[0], v1 = p[1];
    u16 t[8] = {f2bu(v0.x),f2bu(v0.y),f2bu(v0.z),f2bu(v0.w),
                f2bu(v1.x),f2bu(v1.y),f2bu(v1.z),f2bu(v1.w)};
    *reinterpret_cast<uint4*>(out + (size_t)i*8) = *reinterpret_cast<uint4*>(t);
  }
}

// ---------------------------------------------------------------------------
// Per-head softmax: h (S,B,HID) f32 -> xs (B,H,S,D) f32. One wave per 64-row.
// ---------------------------------------------------------------------------
__global__ __launch_bounds__(256) void softmax_xs_k(
    const float* __restrict__ h, float* __restrict__ xs)
{
  int rid  = blockIdx.x*4 + (threadIdx.x>>6);   // (s*B+b)*H + hd
  int lane = threadIdx.x & 63;
  int hd = rid & (H_NUM-1);
  int sb = rid >> 3;                            // s*B + b
  int b  = sb & (B_NUM-1);
  int s  = sb >> 3;
  float v = h[(size_t)sb*HID_D + hd*D_DIM + lane];
  float m = v;
  #pragma unroll
  for (int off=32; off; off>>=1) m = fmaxf(m, __shfl_xor(m, off));
  float e = __expf(v-m);
  float sum = wave_sum(e);
  xs[(((size_t)(b*H_NUM+hd))*S_SEQ + s)*D_DIM + lane] = e/sum;
}

// ---------------------------------------------------------------------------
// SRWM scan, 4 waves per (b,h). x broadcast via SGPRs (s_load) for waves 0-2
// (xs produced by softmax_xs_k in a prior dispatch -> K$ safe).
// q/k/beta in dbuf LDS; 1 barrier/step. (R12-proven structure)
// ---------------------------------------------------------------------------
__global__ __launch_bounds__(256,1) void scan4_k(
    const float* __restrict__ xs,
    const float* __restrict__ st_y, const float* __restrict__ st_q,
    const float* __restrict__ st_k, const float* __restrict__ st_b,
    const float* __restrict__ p_y,  const float* __restrict__ p_q,
    const float* __restrict__ p_k,  const float* __restrict__ p_b,
    u16* __restrict__ y_out,                    // (S,B,HID) bf16
    float* __restrict__ o_sy, float* __restrict__ o_sq,
    float* __restrict__ o_sk, float* __restrict__ o_sb)
{
  const int bh = blockIdx.x;
  const int b  = bh >> 3, hh = bh & 7;
  const int wave = threadIdx.x >> 6, lane = threadIdx.x & 63;

  __shared__ __align__(16) float q_s[2][64];
  __shared__ __align__(16) float k_s[2][64];
  __shared__ float beta_s[2][4];

  float W[64];
  float wb0=0.f, wb1=0.f, wb2=0.f, wb3=0.f;
  float xr[8], xn[8];
  float b3_reg=0.f;
  i32x16 xc0, xc1, xc2, xc3;                    // wave<3: x row in SGPRs

  const float* xbase = xs + (size_t)bh * (S_SEQ*D_DIM);

  if (wave < 3) {
    const float* st = (wave==0)? st_y : (wave==1)? st_q : st_k;
    const float* pp = (wave==0)? p_y  : (wave==1)? p_q  : p_k;
    const float4* s4 = reinterpret_cast<const float4*>(st + ((size_t)bh*64 + lane)*64);
    const float4* p4 = reinterpret_cast<const float4*>(pp + ((size_t)hh*64 + lane)*64);
    #pragma unroll
    for (int c=0;c<16;c++){
      float4 a = s4[c], p = p4[c];
      W[c*4+0]=a.x+p.x; W[c*4+1]=a.y+p.y; W[c*4+2]=a.z+p.z; W[c*4+3]=a.w+p.w;
    }
    sload_x64(xbase, xc0, xc1, xc2, xc3);       // x row for t=0
  } else {
    float4 sv = *reinterpret_cast<const float4*>(st_b + ((size_t)bh*64+lane)*4);
    float4 pv = *reinterpret_cast<const float4*>(p_b  + ((size_t)hh*64+lane)*4);
    wb0 = sv.x+pv.x; wb1 = sv.y+pv.y; wb2 = sv.z+pv.z; wb3 = sv.w+pv.w;
    #pragma unroll
    for (int i=0;i<8;i++) xr[i] = xbase[i*D_DIM + lane];
  }
  __syncthreads();

#define MV16(XV, BASE)                                              \
    _Pragma("unroll")                                               \
    for (int e=0;e<16;e+=4){                                        \
      a0 = fmaf(W[(BASE)+e+0], __int_as_float(XV[e+0]), a0);        \
      a1 = fmaf(W[(BASE)+e+1], __int_as_float(XV[e+1]), a1);        \
      a2 = fmaf(W[(BASE)+e+2], __int_as_float(XV[e+2]), a2);        \
      a3 = fmaf(W[(BASE)+e+3], __int_as_float(XV[e+3]), a3);        \
    }

  for (int t0=0; t0<S_SEQ; t0+=8){
    #pragma unroll
    for (int i=0;i<8;i++){
      const int t = t0 + i;
      const int buf = i & 1;
      // ================ phase A ================
      if (wave < 3){
        asm volatile("s_waitcnt lgkmcnt(0)" ::: "memory");  // s_load done
        float a0=0.f,a1=0.f,a2=0.f,a3=0.f;
        MV16(xc0, 0)
        MV16(xc1, 16)
        MV16(xc2, 32)
        MV16(xc3, 48)
        float r = (a0+a1)+(a2+a3);
        if (wave==0){
          y_out[((size_t)t*B_NUM + b)*HID_D + hh*D_DIM + lane] = f2bu(r);
        } else {
          float e = __expf(r);
          float s = wave_sum(e);
          float val = e * __builtin_amdgcn_rcpf(s);
          (wave==1 ? q_s[buf] : k_s[buf])[lane] = val;
        }
      } else {
        if (i == 0){
          #pragma unroll
          for (int ii=0;ii<8;ii++){
            const int tt = (t0+8+ii) & (S_SEQ-1);
            xn[ii] = xbase[tt*D_DIM + lane];
          }
        }
        float xl = xr[i];
        float s0 = wb0*xl, s1 = wb1*xl, s2 = wb2*xl, s3 = wb3*xl;
        wave_sum4(s0,s1,s2,s3);
        float bb0 = __builtin_amdgcn_rcpf(1.f+__expf(-s0));
        float bb1 = __builtin_amdgcn_rcpf(1.f+__expf(-s1));
        float bb2 = __builtin_amdgcn_rcpf(1.f+__expf(-s2));
        b3_reg    = __builtin_amdgcn_rcpf(1.f+__expf(-s3));
        if (lane==0){
          beta_s[buf][0]=bb0; beta_s[buf][1]=bb1; beta_s[buf][2]=bb2;
          beta_s[buf][3]=b3_reg;
        }
      }
      lds_barrier();
      // ================ phase C ================
      if (wave < 3){
        { // prefetch next x row into SGPRs (hidden under phase C)
          const int tn = (t+1) & (S_SEQ-1);
          sload_x64(xbase + tn*D_DIM, xc0, xc1, xc2, xc3);
        }
        float bw = beta_s[buf][wave];
        float kr[64];
        float a0=0.f,a1=0.f,a2=0.f,a3=0.f;
        #pragma unroll
        for (int j=0;j<16;j++){
          float4 qv = reinterpret_cast<const float4*>(q_s[buf])[j];
          float4 kv = reinterpret_cast<const float4*>(k_s[buf])[j];
          kr[j*4+0]=kv.x; kr[j*4+1]=kv.y; kr[j*4+2]=kv.z; kr[j*4+3]=kv.w;
          a0 = fmaf(W[j*4+0], qv.x-kv.x, a0);
          a1 = fmaf(W[j*4+1], qv.y-kv.y, a1);
          a2 = fmaf(W[j*4+2], qv.z-kv.z, a2);
          a3 = fmaf(W[j*4+3], qv.w-kv.w, a3);
        }
        float rd = (a0+a1)+(a2+a3);
        float cc = bw * rd;
        #pragma unroll
        for (int j=0;j<64;j++)
          W[j] = fmaf(cc, kr[j], W[j]);
      } else {
        float qn = q_s[buf][lane], kn = k_s[buf][lane];
        float dv = qn - kn;
        float d0 = wb0*dv, d1 = wb1*dv, d2 = wb2*dv, d3 = wb3*dv;
        wave_sum4(d0,d1,d2,d3);
        float bk = b3_reg * kn;
        wb0 = fmaf(bk, d0, wb0);
        wb1 = fmaf(bk, d1, wb1);
        wb2 = fmaf(bk, d2, wb2);
        wb3 = fmaf(bk, d3, wb3);
      }
    }
    if (wave == 3){
      #pragma unroll
      for (int i=0;i<8;i++) xr[i] = xn[i];
    }
  }
#undef MV16

  if (wave < 3){
    const float* pp = (wave==0)? p_y : (wave==1)? p_q : p_k;
    float* o = ((wave==0)? o_sy : (wave==1)? o_sq : o_sk) + ((size_t)bh*64 + lane)*64;
    const float4* p4 = reinterpret_cast<const float4*>(pp + ((size_t)hh*64 + lane)*64);
    #pragma unroll
    for (int c=0;c<16;c++){
      float4 p = p4[c];
      float4 w;
      w.x = W[c*4+0]-p.x; w.y = W[c*4+1]-p.y; w.z = W[c*4+2]-p.z; w.w = W[c*4+3]-p.w;
      reinterpret_cast<float4*>(o)[c] = w;
    }
  } else {
    float4 pv = *reinterpret_cast<const float4*>(p_b + ((size_t)hh*64+lane)*4);
    float4 w;
    w.x = wb0-pv.x; w.y = wb1-pv.y; w.z = wb2-pv.z; w.w = wb3-pv.w;
    *reinterpret_cast<float4*>(o_sb + ((size_t)bh*64+lane)*4) = w;
  }
}

// ---------------------------------------------------------------------------
// bf16 MFMA GEMM, bf16 operands: C = A·B^T (+bias)(+Cin)(relu) -> f32 or bf16.
// Tile BMxBN (templated), BK=64, 4 waves (2x2 of BM/2 x BN/2), 16x16x32 MFMA.
// ---------------------------------------------------------------------------
template<int BM,int BN,bool BIAS,bool RELU,bool ADDC,bool OBF>
__global__ __launch_bounds__(256) void mgemm_k(
    const u16* __restrict__ A, const u16* __restrict__ Bw,
    const float* __restrict__ Cin, const float* __restrict__ bias,
    float* __restrict__ Of, u16* __restrict__ Ob,
    int M, int N, int K)
{
  constexpr int BK  = 64;
  constexpr int LDT = 72;                       // u16 row stride (144 B)
  constexpr int WM  = BM/2, WN = BN/2;
  constexpr int FI  = WM/16, FJ = WN/16;
  __shared__ __align__(16) u16 As[BM][LDT];
  __shared__ __align__(16) u16 Bs[BN][LDT];

  const int tid  = threadIdx.x;
  const int wv   = tid >> 6;
  const int lane = tid & 63;
  const int wr   = (wv >> 1) * WM;
  const int wc   = (wv & 1) * WN;
  const int lr   = lane & 15;
  const int lg   = lane >> 4;
  const int m0 = blockIdx.y * BM, n0 = blockIdx.x * BN;

  constexpr int TPRA = 256/BM, CHA = BK/TPRA;
  constexpr int TPRB = 256/BN, CHB = BK/TPRB;
  const int srA = tid / TPRA, skA = (tid % TPRA) * CHA;
  const int srB = tid / TPRB, skB = (tid % TPRB) * CHB;

  f32x4 acc[FI][FJ] = {};

  for (int kt = 0; kt < K; kt += BK){
    {
      const uint4* src = reinterpret_cast<const uint4*>(A + (size_t)(m0+srA)*K + kt + skA);
      uint4* dst = reinterpret_cast<uint4*>(&As[srA][skA]);
      #pragma unroll
      for (int c=0;c<CHA/8;c++) dst[c] = src[c];
    }
    {
      const uint4* src = reinterpret_cast<const uint4*>(Bw + (size_t)(n0+srB)*K + kt + skB);
      uint4* dst = reinterpret_cast<uint4*>(&Bs[srB][skB]);
      #pragma unroll
      for (int c=0;c<CHB/8;c++) dst[c] = src[c];
    }
    __syncthreads();

    #pragma unroll
    for (int half=0; half<2; ++half){
      bf16x8 af[FI], bfb[FJ];
      #pragma unroll
      for (int i=0;i<FI;i++)
        af[i]  = *reinterpret_cast<const bf16x8*>(&As[wr + i*16 + lr][half*32 + lg*8]);
      #pragma unroll
      for (int j=0;j<FJ;j++)
        bfb[j] = *reinterpret_cast<const bf16x8*>(&Bs[wc + j*16 + lr][half*32 + lg*8]);
      #pragma unroll
      for (int i=0;i<FI;i++)
        #pragma unroll
        for (int j=0;j<FJ;j++)
          acc[i][j] = __builtin_amdgcn_mfma_f32_16x16x32_bf16(af[i], bfb[j], acc[i][j], 0,0,0);
    }
    __syncthreads();
  }

  // epilogue: D mapping col=lane&15, row=(lane>>4)*4+dj  [m89-verified]
  #pragma unroll
  for (int j=0;j<FJ;j++){
    const int col = n0 + wc + j*16 + lr;
    float bv = 0.f;
    if (BIAS) bv = bias[col];
    #pragma unroll
    for (int i=0;i<FI;i++){
      const int rbase = m0 + wr + i*16 + lg*4;
      #pragma unroll
      for (int dj=0;dj<4;dj++){
        const int row = rbase + dj;
        float v = acc[i][j][dj];
        if (BIAS) v += bv;
        if (ADDC) v += Cin[(size_t)row*N + col];
        if (RELU) v = fmaxf(v, 0.f);
        if (OBF) Ob[(size_t)row*N + col] = f2bu(v);
        else     Of[(size_t)row*N + col] = v;
      }
    }
  }
}

// ---------------------------------------------------------------------------
// LayerNorm over HID=512, wave per row, 8 elems/lane. f32 -> bf16.
// ---------------------------------------------------------------------------
__global__ __launch_bounds__(256) void ln_k(
    const float* __restrict__ h, const float* __restrict__ g,
    const float* __restrict__ bb, u16* __restrict__ out)
{
  int row  = blockIdx.x*4 + (threadIdx.x>>6);
  int lane = threadIdx.x & 63;
  const float4* hr = reinterpret_cast<const float4*>(h + (size_t)row*HID_D) + lane*2;
  float4 u = hr[0], v = hr[1];
  float vals[8] = {u.x,u.y,u.z,u.w,v.x,v.y,v.z,v.w};
  float s = 0.f;
  #pragma unroll
  for (int e=0;e<8;e++) s += vals[e];
  s = wave_sum(s);
  float mu = s * (1.f/HID_D);
  float vs = 0.f;
  #pragma unroll
  for (int e=0;e<8;e++){ float d = vals[e]-mu; vs += d*d; }
  vs = wave_sum(vs);
  float rs = rsqrtf(vs*(1.f/HID_D) + 1e-5f);
  const float4* gr = reinterpret_cast<const float4*>(g) + lane*2;
  const float4* br = reinterpret_cast<const float4*>(bb) + lane*2;
  float4 g0 = gr[0], g1 = gr[1], b0 = br[0], b1 = br[1];
  u16 ov[8];
  ov[0] = f2bu((vals[0]-mu)*rs*g0.x + b0.x);
  ov[1] = f2bu((vals[1]-mu)*rs*g0.y + b0.y);
  ov[2] = f2bu((vals[2]-mu)*rs*g0.z + b0.z);
  ov[3] = f2bu((vals[3]-mu)*rs*g0.w + b0.w);
  ov[4] = f2bu((vals[4]-mu)*rs*g1.x + b1.x);
  ov[5] = f2bu((vals[5]-mu)*rs*g1.y + b1.y);
  ov[6] = f2bu((vals[6]-mu)*rs*g1.z + b1.z);
  ov[7] = f2bu((vals[7]-mu)*rs*g1.w + b1.w);
  *reinterpret_cast<uint4*>(out + (size_t)row*HID_D + lane*8) =
      *reinterpret_cast<uint4*>(ov);
}

// ---------------------------------------------------------------------------
extern "C" void kernel_launch(void* const* d_in, const int* in_sizes, int n_in,
                              void* d_out, int out_size, void* d_ws, size_t ws_size,
                              hipStream_t stream)
{
  const float* x    = (const float*)d_in[0];
  const float* sty  = (const float*)d_in[1];
  const float* stq  = (const float*)d_in[2];
  const float* stk  = (const float*)d_in[3];
  const float* stb  = (const float*)d_in[4];
  const float* inW  = (const float*)d_in[5];
  const float* inb  = (const float*)d_in[6];
  const float* py   = (const float*)d_in[7];
  const float* pq   = (const float*)d_in[8];
  const float* pk   = (const float*)d_in[9];
  const float* pb   = (const float*)d_in[10];
  const float* Wo   = (const float*)d_in[11];
  const float* fw1  = (const float*)d_in[12];
  const float* fb1  = (const float*)d_in[13];
  const float* fw2  = (const float*)d_in[14];
  const float* fb2  = (const float*)d_in[15];
  const float* lng  = (const float*)d_in[16];
  const float* lnb  = (const float*)d_in[17];

  char* ws = (char*)d_ws;
  float* h    = (float*)ws;                          // 0..4 MB
  float* xsb  = (float*)(ws + (4<<20));              // 4..8 MB
  u16*   yb   = (u16*)  (ws + (8<<20));              // 8..10 MB (bf16 y)
  u16*   t0   = (u16*)  (ws + (10<<20));             // 10..12 MB (bf16 ln out)
  u16*   t1   = (u16*)  (ws + (12<<20));             // 12..20 MB (bf16 ff mid)
  u16*   xb   = (u16*)  (ws + (20<<20));             // 20..22 MB
  u16*   inWb = (u16*)  (ws + (22<<20));             // 0.5 MB
  u16*   Wob  = (u16*)  (ws + (22<<20) + (512*1024));// 1 MB
  u16*   fw1b = (u16*)  (ws + (23<<20) + (512*1024));// 4 MB
  u16*   fw2b = (u16*)  (ws + (27<<20) + (512*1024));// 4 MB (ends 31.5 MB)

  float* out0 = (float*)d_out;
  const size_t OUT_SZ = (size_t)S_SEQ*B_NUM*HID_D;          // 1048576
  const size_t SYL    = (size_t)B_NUM*H_NUM*D_DIM*D_DIM;    // 262144 per layer
  const size_t SBL    = (size_t)B_NUM*H_NUM*D_DIM*4;        // 16384  per layer
  float* o_sy = out0 + OUT_SZ;
  float* o_sq = o_sy + L_NUM*SYL;
  float* o_sk = o_sq + L_NUM*SYL;
  float* o_sb = o_sk + L_NUM*SYL;

  const int M = S_SEQ*B_NUM;   // 2048

  // one-time bf16 conversions (graph-capture safe, deterministic)
  cvt_bf16_k<<<512, 256,0,stream>>>(x,   xb,   M*512/8);
  cvt_bf16_k<<<128, 256,0,stream>>>(inW, inWb, 512*512/8);
  cvt_bf16_k<<<256, 256,0,stream>>>(Wo,  Wob,  L_NUM*512*512/8);
  cvt_bf16_k<<<1024,256,0,stream>>>(fw1, fw1b, L_NUM*FF_D*HID_D/8);
  cvt_bf16_k<<<1024,256,0,stream>>>(fw2, fw2b, L_NUM*HID_D*FF_D/8);

  // in-projection: h = x @ in_W.T + in_b   (64x64 tile -> 256 blocks)
  mgemm_k<64,64,true,false,false,false><<<dim3(HID_D/64, M/64),256,0,stream>>>(
      xb, inWb, nullptr, inb, h, nullptr, M, HID_D, 512);

  for (int l=0;l<L_NUM;l++){
    softmax_xs_k<<<(S_SEQ*B_NUM*H_NUM)/4, 256, 0, stream>>>(h, xsb);

    scan4_k<<<B_NUM*H_NUM, 256, 0, stream>>>(xsb,
        sty + (size_t)l*SYL, stq + (size_t)l*SYL, stk + (size_t)l*SYL, stb + (size_t)l*SBL,
        py + (size_t)l*H_NUM*D_DIM*D_DIM, pq + (size_t)l*H_NUM*D_DIM*D_DIM,
        pk + (size_t)l*H_NUM*D_DIM*D_DIM, pb + (size_t)l*H_NUM*D_DIM*4,
        yb,
        o_sy + l*SYL, o_sq + l*SYL, o_sk + l*SYL, o_sb + l*SBL);

    // h += y @ Wo.T   (64x64 tile -> 256 blocks)
    mgemm_k<64,64,false,false,true,false><<<dim3(HID_D/64, M/64),256,0,stream>>>(
        yb, Wob + (size_t)l*HID_D*HID_D, h, nullptr, h, nullptr, M, HID_D, HID_D);

    ln_k<<<M/4,256,0,stream>>>(h, lng + l*HID_D, lnb + l*HID_D, t0);

    // t1 = relu(ln @ ff_W1.T + b1)  -> bf16  (128x128 tile, 256 blocks)
    mgemm_k<128,128,true,true,false,true><<<dim3(FF_D/128, M/128),256,0,stream>>>(
        t0, fw1b + (size_t)l*FF_D*HID_D, nullptr, fb1 + l*FF_D, nullptr, t1, M, FF_D, HID_D);

    // h(+out) = h + t1 @ ff_W2.T + b2   (64x64 tile -> 256 blocks)
    float* dst = (l==L_NUM-1) ? out0 : h;
    mgemm_k<64,64,true,false,true,false><<<dim3(HID_D/64, M/64),256,0,stream>>>(
        t1, fw2b + (size_t)l*HID_D*FF_D, h, fb2 + l*HID_D, dst, nullptr, M, HID_D, FF_D);
  }
}

// Round 20
// 723.664 us; speedup vs baseline: 1.4696x; 1.0028x over previous
//
#include <hip/hip_runtime.h>

#define L_NUM 2
#define H_NUM 8
#define D_DIM 64
#define HID_D 512
#define FF_D  2048
#define S_SEQ 256
#define B_NUM 8

typedef unsigned short u16;
typedef unsigned int   u32;
typedef __attribute__((ext_vector_type(8))) short bf16x8;
typedef __attribute__((ext_vector_type(4))) float f32x4;
typedef __attribute__((ext_vector_type(16))) int i32x16;

__device__ __forceinline__ u16 f2bu(float f){
  u32 u = __float_as_uint(f);
  u32 r = (u + 0x7fffu + ((u>>16)&1u)) >> 16;   // RNE to bf16
  return (u16)r;
}

template<int CTL,int RM,int BM>
__device__ __forceinline__ float dpp_add_src(float v){
  return __int_as_float(__builtin_amdgcn_update_dpp(0, __float_as_int(v), CTL, RM, BM, false));
}

__device__ __forceinline__ float rlane(float v, int l){
  return __int_as_float(__builtin_amdgcn_readlane(__float_as_int(v), l));
}

// ---------------------------------------------------------------------------
// Wave64 sum, shallow: 4 DPP row_shr levels (exact row sums land in lanes
// 15/31/47/63; 0-identity fill) + 4 parallel readlanes + 3 adds. Exact.
// ---------------------------------------------------------------------------
__device__ __forceinline__ float wave_sum(float v){
  float t;
  t = dpp_add_src<0x111,0xf,0xf>(v); v += t;
  t = dpp_add_src<0x112,0xf,0xf>(v); v += t;
  t = dpp_add_src<0x114,0xf,0xf>(v); v += t;
  t = dpp_add_src<0x118,0xf,0xf>(v); v += t;
  return (rlane(v,15)+rlane(v,31))+(rlane(v,47)+rlane(v,63));
}

// 4 interleaved sums (independent chains share the 4 DPP levels).
__device__ __forceinline__ void wave_sum4(float&a,float&b,float&c,float&d){
  float ta,tb,tc,td;
  ta=dpp_add_src<0x111,0xf,0xf>(a); tb=dpp_add_src<0x111,0xf,0xf>(b);
  tc=dpp_add_src<0x111,0xf,0xf>(c); td=dpp_add_src<0x111,0xf,0xf>(d);
  a+=ta; b+=tb; c+=tc; d+=td;
  ta=dpp_add_src<0x112,0xf,0xf>(a); tb=dpp_add_src<0x112,0xf,0xf>(b);
  tc=dpp_add_src<0x112,0xf,0xf>(c); td=dpp_add_src<0x112,0xf,0xf>(d);
  a+=ta; b+=tb; c+=tc; d+=td;
  ta=dpp_add_src<0x114,0xf,0xf>(a); tb=dpp_add_src<0x114,0xf,0xf>(b);
  tc=dpp_add_src<0x114,0xf,0xf>(c); td=dpp_add_src<0x114,0xf,0xf>(d);
  a+=ta; b+=tb; c+=tc; d+=td;
  ta=dpp_add_src<0x118,0xf,0xf>(a); tb=dpp_add_src<0x118,0xf,0xf>(b);
  tc=dpp_add_src<0x118,0xf,0xf>(c); td=dpp_add_src<0x118,0xf,0xf>(d);
  a+=ta; b+=tb; c+=tc; d+=td;
  a = (rlane(a,15)+rlane(a,31))+(rlane(a,47)+rlane(a,63));
  b = (rlane(b,15)+rlane(b,31))+(rlane(b,47)+rlane(b,63));
  c = (rlane(c,15)+rlane(c,31))+(rlane(c,47)+rlane(c,63));
  d = (rlane(d,15)+rlane(d,31))+(rlane(d,47)+rlane(d,63));
}

// LDS-only barrier: does NOT drain vmcnt (global ops stay in flight).
__device__ __forceinline__ void lds_barrier(){
  __builtin_amdgcn_sched_barrier(0);
  asm volatile("s_waitcnt lgkmcnt(0)" ::: "memory");
  __builtin_amdgcn_s_barrier();
  __builtin_amdgcn_sched_barrier(0);
}

// Uniform 64-float row -> 64 SGPRs (4x s_load_dwordx16). Pointer MUST be
// provably uniform. Only safe for data produced by a PRIOR kernel.
__device__ __forceinline__ void sload_x64(const float* p,
    i32x16& a, i32x16& b, i32x16& c, i32x16& d){
  asm volatile(
    "s_load_dwordx16 %0, %4, 0x0\n\t"
    "s_load_dwordx16 %1, %4, 0x40\n\t"
    "s_load_dwordx16 %2, %4, 0x80\n\t"
    "s_load_dwordx16 %3, %4, 0xC0"
    : "=&s"(a), "=&s"(b), "=&s"(c), "=&s"(d)
    : "s"((unsigned long long)(__SIZE_TYPE__)p));
}

// ---------------------------------------------------------------------------
// f32 -> bf16 convert, 8 elems/thread.
// ---------------------------------------------------------------------------
__global__ __launch_bounds__(256) void cvt_bf16_k(
    const float* __restrict__ in, u16* __restrict__ out, int n8)
{
  int i = blockIdx.x*256 + threadIdx.x;
  if (i < n8){
    const float4* p = reinterpret_cast<const float4*>(in + (size_t)i*8);
    float4 v0 = p[0], v1 = p[1];
    u16 t[8] = {f2bu(v0.x),f2bu(v0.y),f2bu(v0.z),f2bu(v0.w),
                f2bu(v1.x),f2bu(v1.y),f2bu(v1.z),f2bu(v1.w)};
    *reinterpret_cast<uint4*>(out + (size_t)i*8) = *reinterpret_cast<uint4*>(t);
  }
}

// ---------------------------------------------------------------------------
// Per-head softmax: h (S,B,HID) f32 -> xs (B,H,S,D) f32. One wave per 64-row.
// ---------------------------------------------------------------------------
__global__ __launch_bounds__(256) void softmax_xs_k(
    const float* __restrict__ h, float* __restrict__ xs)
{
  int rid  = blockIdx.x*4 + (threadIdx.x>>6);   // (s*B+b)*H + hd
  int lane = threadIdx.x & 63;
  int hd = rid & (H_NUM-1);
  int sb = rid >> 3;                            // s*B + b
  int b  = sb & (B_NUM-1);
  int s  = sb >> 3;
  float v = h[(size_t)sb*HID_D + hd*D_DIM + lane];
  float m = v;
  #pragma unroll
  for (int off=32; off; off>>=1) m = fmaxf(m, __shfl_xor(m, off));
  float e = __expf(v-m);
  float sum = wave_sum(e);
  xs[(((size_t)(b*H_NUM+hd))*S_SEQ + s)*D_DIM + lane] = e/sum;
}

// ---------------------------------------------------------------------------
// SRWM scan, 4 waves per (b,h). x broadcast via SGPRs (s_load) for waves 0-2
// (xs produced by softmax_xs_k in a prior dispatch -> K$ safe).
// q/k/beta in dbuf LDS; 1 barrier/step. (R18-verified: 286 us)
// ---------------------------------------------------------------------------
__global__ __launch_bounds__(256,1) void scan4_k(
    const float* __restrict__ xs,
    const float* __restrict__ st_y, const float* __restrict__ st_q,
    const float* __restrict__ st_k, const float* __restrict__ st_b,
    const float* __restrict__ p_y,  const float* __restrict__ p_q,
    const float* __restrict__ p_k,  const float* __restrict__ p_b,
    u16* __restrict__ y_out,                    // (S,B,HID) bf16
    float* __restrict__ o_sy, float* __restrict__ o_sq,
    float* __restrict__ o_sk, float* __restrict__ o_sb)
{
  const int bh = blockIdx.x;
  const int b  = bh >> 3, hh = bh & 7;
  const int wave = threadIdx.x >> 6, lane = threadIdx.x & 63;

  __shared__ __align__(16) float q_s[2][64];
  __shared__ __align__(16) float k_s[2][64];
  __shared__ float beta_s[2][4];

  float W[64];
  float wb0=0.f, wb1=0.f, wb2=0.f, wb3=0.f;
  float xr[8], xn[8];
  float b3_reg=0.f;
  i32x16 xc0, xc1, xc2, xc3;                    // wave<3: x row in SGPRs

  const float* xbase = xs + (size_t)bh * (S_SEQ*D_DIM);

  if (wave < 3) {
    const float* st = (wave==0)? st_y : (wave==1)? st_q : st_k;
    const float* pp = (wave==0)? p_y  : (wave==1)? p_q  : p_k;
    const float4* s4 = reinterpret_cast<const float4*>(st + ((size_t)bh*64 + lane)*64);
    const float4* p4 = reinterpret_cast<const float4*>(pp + ((size_t)hh*64 + lane)*64);
    #pragma unroll
    for (int c=0;c<16;c++){
      float4 a = s4[c], p = p4[c];
      W[c*4+0]=a.x+p.x; W[c*4+1]=a.y+p.y; W[c*4+2]=a.z+p.z; W[c*4+3]=a.w+p.w;
    }
    sload_x64(xbase, xc0, xc1, xc2, xc3);       // x row for t=0
  } else {
    float4 sv = *reinterpret_cast<const float4*>(st_b + ((size_t)bh*64+lane)*4);
    float4 pv = *reinterpret_cast<const float4*>(p_b  + ((size_t)hh*64+lane)*4);
    wb0 = sv.x+pv.x; wb1 = sv.y+pv.y; wb2 = sv.z+pv.z; wb3 = sv.w+pv.w;
    #pragma unroll
    for (int i=0;i<8;i++) xr[i] = xbase[i*D_DIM + lane];
  }
  __syncthreads();

#define MV16(XV, BASE)                                              \
    _Pragma("unroll")                                               \
    for (int e=0;e<16;e+=4){                                        \
      a0 = fmaf(W[(BASE)+e+0], __int_as_float(XV[e+0]), a0);        \
      a1 = fmaf(W[(BASE)+e+1], __int_as_float(XV[e+1]), a1);        \
      a2 = fmaf(W[(BASE)+e+2], __int_as_float(XV[e+2]), a2);        \
      a3 = fmaf(W[(BASE)+e+3], __int_as_float(XV[e+3]), a3);        \
    }

  for (int t0=0; t0<S_SEQ; t0+=8){
    #pragma unroll
    for (int i=0;i<8;i++){
      const int t = t0 + i;
      const int buf = i & 1;
      // ================ phase A ================
      if (wave < 3){
        asm volatile("s_waitcnt lgkmcnt(0)" ::: "memory");  // s_load done
        float a0=0.f,a1=0.f,a2=0.f,a3=0.f;
        MV16(xc0, 0)
        MV16(xc1, 16)
        MV16(xc2, 32)
        MV16(xc3, 48)
        float r = (a0+a1)+(a2+a3);
        if (wave==0){
          y_out[((size_t)t*B_NUM + b)*HID_D + hh*D_DIM + lane] = f2bu(r);
        } else {
          float e = __expf(r);
          float s = wave_sum(e);
          float val = e * __builtin_amdgcn_rcpf(s);
          (wave==1 ? q_s[buf] : k_s[buf])[lane] = val;
        }
      } else {
        if (i == 0){
          #pragma unroll
          for (int ii=0;ii<8;ii++){
            const int tt = (t0+8+ii) & (S_SEQ-1);
            xn[ii] = xbase[tt*D_DIM + lane];
          }
        }
        float xl = xr[i];
        float s0 = wb0*xl, s1 = wb1*xl, s2 = wb2*xl, s3 = wb3*xl;
        wave_sum4(s0,s1,s2,s3);
        float bb0 = __builtin_amdgcn_rcpf(1.f+__expf(-s0));
        float bb1 = __builtin_amdgcn_rcpf(1.f+__expf(-s1));
        float bb2 = __builtin_amdgcn_rcpf(1.f+__expf(-s2));
        b3_reg    = __builtin_amdgcn_rcpf(1.f+__expf(-s3));
        if (lane==0){
          beta_s[buf][0]=bb0; beta_s[buf][1]=bb1; beta_s[buf][2]=bb2;
          beta_s[buf][3]=b3_reg;
        }
      }
      lds_barrier();
      // ================ phase C ================
      if (wave < 3){
        { // prefetch next x row into SGPRs (hidden under phase C)
          const int tn = (t+1) & (S_SEQ-1);
          sload_x64(xbase + tn*D_DIM, xc0, xc1, xc2, xc3);
        }
        float bw = beta_s[buf][wave];
        float kr[64];
        float a0=0.f,a1=0.f,a2=0.f,a3=0.f;
        #pragma unroll
        for (int j=0;j<16;j++){
          float4 qv = reinterpret_cast<const float4*>(q_s[buf])[j];
          float4 kv = reinterpret_cast<const float4*>(k_s[buf])[j];
          kr[j*4+0]=kv.x; kr[j*4+1]=kv.y; kr[j*4+2]=kv.z; kr[j*4+3]=kv.w;
          a0 = fmaf(W[j*4+0], qv.x-kv.x, a0);
          a1 = fmaf(W[j*4+1], qv.y-kv.y, a1);
          a2 = fmaf(W[j*4+2], qv.z-kv.z, a2);
          a3 = fmaf(W[j*4+3], qv.w-kv.w, a3);
        }
        float rd = (a0+a1)+(a2+a3);
        float cc = bw * rd;
        #pragma unroll
        for (int j=0;j<64;j++)
          W[j] = fmaf(cc, kr[j], W[j]);
      } else {
        float qn = q_s[buf][lane], kn = k_s[buf][lane];
        float dv = qn - kn;
        float d0 = wb0*dv, d1 = wb1*dv, d2 = wb2*dv, d3 = wb3*dv;
        wave_sum4(d0,d1,d2,d3);
        float bk = b3_reg * kn;
        wb0 = fmaf(bk, d0, wb0);
        wb1 = fmaf(bk, d1, wb1);
        wb2 = fmaf(bk, d2, wb2);
        wb3 = fmaf(bk, d3, wb3);
      }
    }
    if (wave == 3){
      #pragma unroll
      for (int i=0;i<8;i++) xr[i] = xn[i];
    }
  }
#undef MV16

  if (wave < 3){
    const float* pp = (wave==0)? p_y : (wave==1)? p_q : p_k;
    float* o = ((wave==0)? o_sy : (wave==1)? o_sq : o_sk) + ((size_t)bh*64 + lane)*64;
    const float4* p4 = reinterpret_cast<const float4*>(pp + ((size_t)hh*64 + lane)*64);
    #pragma unroll
    for (int c=0;c<16;c++){
      float4 p = p4[c];
      float4 w;
      w.x = W[c*4+0]-p.x; w.y = W[c*4+1]-p.y; w.z = W[c*4+2]-p.z; w.w = W[c*4+3]-p.w;
      reinterpret_cast<float4*>(o)[c] = w;
    }
  } else {
    float4 pv = *reinterpret_cast<const float4*>(p_b + ((size_t)hh*64+lane)*4);
    float4 w;
    w.x = wb0-pv.x; w.y = wb1-pv.y; w.z = wb2-pv.z; w.w = wb3-pv.w;
    *reinterpret_cast<float4*>(o_sb + ((size_t)bh*64+lane)*4) = w;
  }
}

// ---------------------------------------------------------------------------
// bf16 MFMA GEMM, bf16 operands: C = A·B^T (+bias)(+Cin)(relu) -> f32 or bf16.
// Tile BMxBN (templated), BK=64, 4 waves (2x2 of BM/2 x BN/2), 16x16x32 MFMA.
// ---------------------------------------------------------------------------
template<int BM,int BN,bool BIAS,bool RELU,bool ADDC,bool OBF>
__global__ __launch_bounds__(256) void mgemm_k(
    const u16* __restrict__ A, const u16* __restrict__ Bw,
    const float* __restrict__ Cin, const float* __restrict__ bias,
    float* __restrict__ Of, u16* __restrict__ Ob,
    int M, int N, int K)
{
  constexpr int BK  = 64;
  constexpr int LDT = 72;                       // u16 row stride (144 B)
  constexpr int WM  = BM/2, WN = BN/2;
  constexpr int FI  = WM/16, FJ = WN/16;
  __shared__ __align__(16) u16 As[BM][LDT];
  __shared__ __align__(16) u16 Bs[BN][LDT];

  const int tid  = threadIdx.x;
  const int wv   = tid >> 6;
  const int lane = tid & 63;
  const int wr   = (wv >> 1) * WM;
  const int wc   = (wv & 1) * WN;
  const int lr   = lane & 15;
  const int lg   = lane >> 4;
  const int m0 = blockIdx.y * BM, n0 = blockIdx.x * BN;

  constexpr int TPRA = 256/BM, CHA = BK/TPRA;
  constexpr int TPRB = 256/BN, CHB = BK/TPRB;
  const int srA = tid / TPRA, skA = (tid % TPRA) * CHA;
  const int srB = tid / TPRB, skB = (tid % TPRB) * CHB;

  f32x4 acc[FI][FJ] = {};

  for (int kt = 0; kt < K; kt += BK){
    {
      const uint4* src = reinterpret_cast<const uint4*>(A + (size_t)(m0+srA)*K + kt + skA);
      uint4* dst = reinterpret_cast<uint4*>(&As[srA][skA]);
      #pragma unroll
      for (int c=0;c<CHA/8;c++) dst[c] = src[c];
    }
    {
      const uint4* src = reinterpret_cast<const uint4*>(Bw + (size_t)(n0+srB)*K + kt + skB);
      uint4* dst = reinterpret_cast<uint4*>(&Bs[srB][skB]);
      #pragma unroll
      for (int c=0;c<CHB/8;c++) dst[c] = src[c];
    }
    __syncthreads();

    #pragma unroll
    for (int half=0; half<2; ++half){
      bf16x8 af[FI], bfb[FJ];
      #pragma unroll
      for (int i=0;i<FI;i++)
        af[i]  = *reinterpret_cast<const bf16x8*>(&As[wr + i*16 + lr][half*32 + lg*8]);
      #pragma unroll
      for (int j=0;j<FJ;j++)
        bfb[j] = *reinterpret_cast<const bf16x8*>(&Bs[wc + j*16 + lr][half*32 + lg*8]);
      #pragma unroll
      for (int i=0;i<FI;i++)
        #pragma unroll
        for (int j=0;j<FJ;j++)
          acc[i][j] = __builtin_amdgcn_mfma_f32_16x16x32_bf16(af[i], bfb[j], acc[i][j], 0,0,0);
    }
    __syncthreads();
  }

  // epilogue: D mapping col=lane&15, row=(lane>>4)*4+dj  [m89-verified]
  #pragma unroll
  for (int j=0;j<FJ;j++){
    const int col = n0 + wc + j*16 + lr;
    float bv = 0.f;
    if (BIAS) bv = bias[col];
    #pragma unroll
    for (int i=0;i<FI;i++){
      const int rbase = m0 + wr + i*16 + lg*4;
      #pragma unroll
      for (int dj=0;dj<4;dj++){
        const int row = rbase + dj;
        float v = acc[i][j][dj];
        if (BIAS) v += bv;
        if (ADDC) v += Cin[(size_t)row*N + col];
        if (RELU) v = fmaxf(v, 0.f);
        if (OBF) Ob[(size_t)row*N + col] = f2bu(v);
        else     Of[(size_t)row*N + col] = v;
      }
    }
  }
}

// ---------------------------------------------------------------------------
// LayerNorm over HID=512, wave per row, 8 elems/lane. f32 -> bf16.
// ---------------------------------------------------------------------------
__global__ __launch_bounds__(256) void ln_k(
    const float* __restrict__ h, const float* __restrict__ g,
    const float* __restrict__ bb, u16* __restrict__ out)
{
  int row  = blockIdx.x*4 + (threadIdx.x>>6);
  int lane = threadIdx.x & 63;
  const float4* hr = reinterpret_cast<const float4*>(h + (size_t)row*HID_D) + lane*2;
  float4 u = hr[0], v = hr[1];
  float vals[8] = {u.x,u.y,u.z,u.w,v.x,v.y,v.z,v.w};
  float s = 0.f;
  #pragma unroll
  for (int e=0;e<8;e++) s += vals[e];
  s = wave_sum(s);
  float mu = s * (1.f/HID_D);
  float vs = 0.f;
  #pragma unroll
  for (int e=0;e<8;e++){ float d = vals[e]-mu; vs += d*d; }
  vs = wave_sum(vs);
  float rs = rsqrtf(vs*(1.f/HID_D) + 1e-5f);
  const float4* gr = reinterpret_cast<const float4*>(g) + lane*2;
  const float4* br = reinterpret_cast<const float4*>(bb) + lane*2;
  float4 g0 = gr[0], g1 = gr[1], b0 = br[0], b1 = br[1];
  u16 ov[8];
  ov[0] = f2bu((vals[0]-mu)*rs*g0.x + b0.x);
  ov[1] = f2bu((vals[1]-mu)*rs*g0.y + b0.y);
  ov[2] = f2bu((vals[2]-mu)*rs*g0.z + b0.z);
  ov[3] = f2bu((vals[3]-mu)*rs*g0.w + b0.w);
  ov[4] = f2bu((vals[4]-mu)*rs*g1.x + b1.x);
  ov[5] = f2bu((vals[5]-mu)*rs*g1.y + b1.y);
  ov[6] = f2bu((vals[6]-mu)*rs*g1.z + b1.z);
  ov[7] = f2bu((vals[7]-mu)*rs*g1.w + b1.w);
  *reinterpret_cast<uint4*>(out + (size_t)row*HID_D + lane*8) =
      *reinterpret_cast<uint4*>(ov);
}

// ---------------------------------------------------------------------------
extern "C" void kernel_launch(void* const* d_in, const int* in_sizes, int n_in,
                              void* d_out, int out_size, void* d_ws, size_t ws_size,
                              hipStream_t stream)
{
  const float* x    = (const float*)d_in[0];
  const float* sty  = (const float*)d_in[1];
  const float* stq  = (const float*)d_in[2];
  const float* stk  = (const float*)d_in[3];
  const float* stb  = (const float*)d_in[4];
  const float* inW  = (const float*)d_in[5];
  const float* inb  = (const float*)d_in[6];
  const float* py   = (const float*)d_in[7];
  const float* pq   = (const float*)d_in[8];
  const float* pk   = (const float*)d_in[9];
  const float* pb   = (const float*)d_in[10];
  const float* Wo   = (const float*)d_in[11];
  const float* fw1  = (const float*)d_in[12];
  const float* fb1  = (const float*)d_in[13];
  const float* fw2  = (const float*)d_in[14];
  const float* fb2  = (const float*)d_in[15];
  const float* lng  = (const float*)d_in[16];
  const float* lnb  = (const float*)d_in[17];

  char* ws = (char*)d_ws;
  float* h    = (float*)ws;                          // 0..4 MB
  float* xsb  = (float*)(ws + (4<<20));              // 4..8 MB
  u16*   yb   = (u16*)  (ws + (8<<20));              // 8..10 MB (bf16 y)
  u16*   t0   = (u16*)  (ws + (10<<20));             // 10..12 MB (bf16 ln out)
  u16*   t1   = (u16*)  (ws + (12<<20));             // 12..20 MB (bf16 ff mid)
  u16*   xb   = (u16*)  (ws + (20<<20));             // 20..22 MB
  u16*   inWb = (u16*)  (ws + (22<<20));             // 0.5 MB
  u16*   Wob  = (u16*)  (ws + (22<<20) + (512*1024));// 1 MB
  u16*   fw1b = (u16*)  (ws + (23<<20) + (512*1024));// 4 MB
  u16*   fw2b = (u16*)  (ws + (27<<20) + (512*1024));// 4 MB (ends 31.5 MB)

  float* out0 = (float*)d_out;
  const size_t OUT_SZ = (size_t)S_SEQ*B_NUM*HID_D;          // 1048576
  const size_t SYL    = (size_t)B_NUM*H_NUM*D_DIM*D_DIM;    // 262144 per layer
  const size_t SBL    = (size_t)B_NUM*H_NUM*D_DIM*4;        // 16384  per layer
  float* o_sy = out0 + OUT_SZ;
  float* o_sq = o_sy + L_NUM*SYL;
  float* o_sk = o_sq + L_NUM*SYL;
  float* o_sb = o_sk + L_NUM*SYL;

  const int M = S_SEQ*B_NUM;   // 2048

  // one-time bf16 conversions (graph-capture safe, deterministic)
  cvt_bf16_k<<<512, 256,0,stream>>>(x,   xb,   M*512/8);
  cvt_bf16_k<<<128, 256,0,stream>>>(inW, inWb, 512*512/8);
  cvt_bf16_k<<<256, 256,0,stream>>>(Wo,  Wob,  L_NUM*512*512/8);
  cvt_bf16_k<<<1024,256,0,stream>>>(fw1, fw1b, L_NUM*FF_D*HID_D/8);
  cvt_bf16_k<<<1024,256,0,stream>>>(fw2, fw2b, L_NUM*HID_D*FF_D/8);

  // in-projection: h = x @ in_W.T + in_b   (64x64 tile -> 256 blocks)
  mgemm_k<64,64,true,false,false,false><<<dim3(HID_D/64, M/64),256,0,stream>>>(
      xb, inWb, nullptr, inb, h, nullptr, M, HID_D, 512);

  for (int l=0;l<L_NUM;l++){
    softmax_xs_k<<<(S_SEQ*B_NUM*H_NUM)/4, 256, 0, stream>>>(h, xsb);

    scan4_k<<<B_NUM*H_NUM, 256, 0, stream>>>(xsb,
        sty + (size_t)l*SYL, stq + (size_t)l*SYL, stk + (size_t)l*SYL, stb + (size_t)l*SBL,
        py + (size_t)l*H_NUM*D_DIM*D_DIM, pq + (size_t)l*H_NUM*D_DIM*D_DIM,
        pk + (size_t)l*H_NUM*D_DIM*D_DIM, pb + (size_t)l*H_NUM*D_DIM*4,
        yb,
        o_sy + l*SYL, o_sq + l*SYL, o_sk + l*SYL, o_sb + l*SBL);

    // h += y @ Wo.T   (64x64 tile -> 256 blocks)
    mgemm_k<64,64,false,false,true,false><<<dim3(HID_D/64, M/64),256,0,stream>>>(
        yb, Wob + (size_t)l*HID_D*HID_D, h, nullptr, h, nullptr, M, HID_D, HID_D);

    ln_k<<<M/4,256,0,stream>>>(h, lng + l*HID_D, lnb + l*HID_D, t0);

    // t1 = relu(ln @ ff_W1.T + b1)  -> bf16  (128x128 tile, 256 blocks)
    mgemm_k<128,128,true,true,false,true><<<dim3(FF_D/128, M/128),256,0,stream>>>(
        t0, fw1b + (size_t)l*FF_D*HID_D, nullptr, fb1 + l*FF_D, nullptr, t1, M, FF_D, HID_D);

    // h(+out) = h + t1 @ ff_W2.T + b2   (64x64 tile -> 256 blocks)
    float* dst = (l==L_NUM-1) ? out0 : h;
    mgemm_k<64,64,true,false,true,false><<<dim3(HID_D/64, M/64),256,0,stream>>>(
        t1, fw2b + (size_t)l*HID_D*FF_D, h, fb2 + l*HID_D, dst, nullptr, M, HID_D, FF_D);
  }
}

// Round 21
// 641.954 us; speedup vs baseline: 1.6567x; 1.1273x over previous
//
#include <hip/hip_runtime.h>

#define L_NUM 2
#define H_NUM 8
#define D_DIM 64
#define HID_D 512
#define FF_D  2048
#define S_SEQ 256
#define B_NUM 8

typedef unsigned short u16;
typedef unsigned int   u32;
typedef __attribute__((ext_vector_type(8))) short bf16x8;
typedef __attribute__((ext_vector_type(4))) float f32x4;
typedef __attribute__((ext_vector_type(16))) int i32x16;

__device__ __forceinline__ u16 f2bu(float f){
  u32 u = __float_as_uint(f);
  u32 r = (u + 0x7fffu + ((u>>16)&1u)) >> 16;   // RNE to bf16
  return (u16)r;
}

template<int CTL,int RM,int BM>
__device__ __forceinline__ float dpp_add_src(float v){
  return __int_as_float(__builtin_amdgcn_update_dpp(0, __float_as_int(v), CTL, RM, BM, false));
}

__device__ __forceinline__ float rlane(float v, int l){
  return __int_as_float(__builtin_amdgcn_readlane(__float_as_int(v), l));
}

// ---------------------------------------------------------------------------
// Wave64 sum, shallow: 4 DPP row_shr levels (exact row sums land in lanes
// 15/31/47/63; 0-identity fill) + 4 parallel readlanes + 3 adds. Exact.
// ---------------------------------------------------------------------------
__device__ __forceinline__ float wave_sum(float v){
  float t;
  t = dpp_add_src<0x111,0xf,0xf>(v); v += t;
  t = dpp_add_src<0x112,0xf,0xf>(v); v += t;
  t = dpp_add_src<0x114,0xf,0xf>(v); v += t;
  t = dpp_add_src<0x118,0xf,0xf>(v); v += t;
  return (rlane(v,15)+rlane(v,31))+(rlane(v,47)+rlane(v,63));
}

// 4 interleaved sums (independent chains share the 4 DPP levels).
__device__ __forceinline__ void wave_sum4(float&a,float&b,float&c,float&d){
  float ta,tb,tc,td;
  ta=dpp_add_src<0x111,0xf,0xf>(a); tb=dpp_add_src<0x111,0xf,0xf>(b);
  tc=dpp_add_src<0x111,0xf,0xf>(c); td=dpp_add_src<0x111,0xf,0xf>(d);
  a+=ta; b+=tb; c+=tc; d+=td;
  ta=dpp_add_src<0x112,0xf,0xf>(a); tb=dpp_add_src<0x112,0xf,0xf>(b);
  tc=dpp_add_src<0x112,0xf,0xf>(c); td=dpp_add_src<0x112,0xf,0xf>(d);
  a+=ta; b+=tb; c+=tc; d+=td;
  ta=dpp_add_src<0x114,0xf,0xf>(a); tb=dpp_add_src<0x114,0xf,0xf>(b);
  tc=dpp_add_src<0x114,0xf,0xf>(c); td=dpp_add_src<0x114,0xf,0xf>(d);
  a+=ta; b+=tb; c+=tc; d+=td;
  ta=dpp_add_src<0x118,0xf,0xf>(a); tb=dpp_add_src<0x118,0xf,0xf>(b);
  tc=dpp_add_src<0x118,0xf,0xf>(c); td=dpp_add_src<0x118,0xf,0xf>(d);
  a+=ta; b+=tb; c+=tc; d+=td;
  a = (rlane(a,15)+rlane(a,31))+(rlane(a,47)+rlane(a,63));
  b = (rlane(b,15)+rlane(b,31))+(rlane(b,47)+rlane(b,63));
  c = (rlane(c,15)+rlane(c,31))+(rlane(c,47)+rlane(c,63));
  d = (rlane(d,15)+rlane(d,31))+(rlane(d,47)+rlane(d,63));
}

// LDS-only barrier: does NOT drain vmcnt (global ops stay in flight).
__device__ __forceinline__ void lds_barrier(){
  __builtin_amdgcn_sched_barrier(0);
  asm volatile("s_waitcnt lgkmcnt(0)" ::: "memory");
  __builtin_amdgcn_s_barrier();
  __builtin_amdgcn_sched_barrier(0);
}

// Uniform 64-float row -> 64 SGPRs (4x s_load_dwordx16). Pointer MUST be
// provably uniform. Only safe for data produced by a PRIOR kernel.
__device__ __forceinline__ void sload_x64(const float* p,
    i32x16& a, i32x16& b, i32x16& c, i32x16& d){
  asm volatile(
    "s_load_dwordx16 %0, %4, 0x0\n\t"
    "s_load_dwordx16 %1, %4, 0x40\n\t"
    "s_load_dwordx16 %2, %4, 0x80\n\t"
    "s_load_dwordx16 %3, %4, 0xC0"
    : "=&s"(a), "=&s"(b), "=&s"(c), "=&s"(d)
    : "s"((unsigned long long)(__SIZE_TYPE__)p));
}

// ---------------------------------------------------------------------------
// f32 -> bf16 convert, 8 elems/thread.
// ---------------------------------------------------------------------------
__global__ __launch_bounds__(256) void cvt_bf16_k(
    const float* __restrict__ in, u16* __restrict__ out, int n8)
{
  int i = blockIdx.x*256 + threadIdx.x;
  if (i < n8){
    const float4* p = reinterpret_cast<const float4*>(in + (size_t)i*8);
    float4 v0 = p[0], v1 = p[1];
    u16 t[8] = {f2bu(v0.x),f2bu(v0.y),f2bu(v0.z),f2bu(v0.w),
                f2bu(v1.x),f2bu(v1.y),f2bu(v1.z),f2bu(v1.w)};
    *reinterpret_cast<uint4*>(out + (size_t)i*8) = *reinterpret_cast<uint4*>(t);
  }
}

// ---------------------------------------------------------------------------
// Per-head softmax: h (S,B,HID) f32 -> xs (B,H,S,D) f32. One wave per 64-row.
// ---------------------------------------------------------------------------
__global__ __launch_bounds__(256) void softmax_xs_k(
    const float* __restrict__ h, float* __restrict__ xs)
{
  int rid  = blockIdx.x*4 + (threadIdx.x>>6);   // (s*B+b)*H + hd
  int lane = threadIdx.x & 63;
  int hd = rid & (H_NUM-1);
  int sb = rid >> 3;                            // s*B + b
  int b  = sb & (B_NUM-1);
  int s  = sb >> 3;
  float v = h[(size_t)sb*HID_D + hd*D_DIM + lane];
  float m = v;
  #pragma unroll
  for (int off=32; off; off>>=1) m = fmaxf(m, __shfl_xor(m, off));
  float e = __expf(v-m);
  float sum = wave_sum(e);
  xs[(((size_t)(b*H_NUM+hd))*S_SEQ + s)*D_DIM + lane] = e/sum;
}

// ---------------------------------------------------------------------------
// SRWM scan, 4 waves per (b,h). x via SGPR s_loads (prior-kernel data -> K$
// safe). q/k stored as bf16 in LDS (halves phase-C broadcast LDS traffic).
// Identical structure to the R18-verified kernel otherwise; sload prefetch
// kept at its R18 position (start of phase C), no scheduler fences added.
// ---------------------------------------------------------------------------
__global__ __launch_bounds__(256,1) void scan4_k(
    const float* __restrict__ xs,
    const float* __restrict__ st_y, const float* __restrict__ st_q,
    const float* __restrict__ st_k, const float* __restrict__ st_b,
    const float* __restrict__ p_y,  const float* __restrict__ p_q,
    const float* __restrict__ p_k,  const float* __restrict__ p_b,
    u16* __restrict__ y_out,                    // (S,B,HID) bf16
    float* __restrict__ o_sy, float* __restrict__ o_sq,
    float* __restrict__ o_sk, float* __restrict__ o_sb)
{
  const int bh = blockIdx.x;
  const int b  = bh >> 3, hh = bh & 7;
  const int wave = threadIdx.x >> 6, lane = threadIdx.x & 63;

  __shared__ __align__(16) u16 q_s[2][64];      // bf16 q
  __shared__ __align__(16) u16 k_s[2][64];      // bf16 k
  __shared__ float beta_s[2][4];

  float W[64];
  float wb0=0.f, wb1=0.f, wb2=0.f, wb3=0.f;
  float xr[8], xn[8];
  float b3_reg=0.f;
  i32x16 xc0, xc1, xc2, xc3;                    // wave<3: x row in SGPRs

  const float* xbase = xs + (size_t)bh * (S_SEQ*D_DIM);

  if (wave < 3) {
    const float* st = (wave==0)? st_y : (wave==1)? st_q : st_k;
    const float* pp = (wave==0)? p_y  : (wave==1)? p_q  : p_k;
    const float4* s4 = reinterpret_cast<const float4*>(st + ((size_t)bh*64 + lane)*64);
    const float4* p4 = reinterpret_cast<const float4*>(pp + ((size_t)hh*64 + lane)*64);
    #pragma unroll
    for (int c=0;c<16;c++){
      float4 a = s4[c], p = p4[c];
      W[c*4+0]=a.x+p.x; W[c*4+1]=a.y+p.y; W[c*4+2]=a.z+p.z; W[c*4+3]=a.w+p.w;
    }
    sload_x64(xbase, xc0, xc1, xc2, xc3);       // x row for t=0
  } else {
    float4 sv = *reinterpret_cast<const float4*>(st_b + ((size_t)bh*64+lane)*4);
    float4 pv = *reinterpret_cast<const float4*>(p_b  + ((size_t)hh*64+lane)*4);
    wb0 = sv.x+pv.x; wb1 = sv.y+pv.y; wb2 = sv.z+pv.z; wb3 = sv.w+pv.w;
    #pragma unroll
    for (int i=0;i<8;i++) xr[i] = xbase[i*D_DIM + lane];
  }
  __syncthreads();

#define MV16(XV, BASE)                                              \
    _Pragma("unroll")                                               \
    for (int e=0;e<16;e+=4){                                        \
      a0 = fmaf(W[(BASE)+e+0], __int_as_float(XV[e+0]), a0);        \
      a1 = fmaf(W[(BASE)+e+1], __int_as_float(XV[e+1]), a1);        \
      a2 = fmaf(W[(BASE)+e+2], __int_as_float(XV[e+2]), a2);        \
      a3 = fmaf(W[(BASE)+e+3], __int_as_float(XV[e+3]), a3);        \
    }

  for (int t0=0; t0<S_SEQ; t0+=8){
    #pragma unroll
    for (int i=0;i<8;i++){
      const int t = t0 + i;
      const int buf = i & 1;
      // ================ phase A ================
      if (wave < 3){
        asm volatile("s_waitcnt lgkmcnt(0)" ::: "memory");  // s_load done
        float a0=0.f,a1=0.f,a2=0.f,a3=0.f;
        MV16(xc0, 0)
        MV16(xc1, 16)
        MV16(xc2, 32)
        MV16(xc3, 48)
        float r = (a0+a1)+(a2+a3);
        if (wave==0){
          y_out[((size_t)t*B_NUM + b)*HID_D + hh*D_DIM + lane] = f2bu(r);
        } else {
          float e = __expf(r);
          float s = wave_sum(e);
          float val = e * __builtin_amdgcn_rcpf(s);
          (wave==1 ? q_s[buf] : k_s[buf])[lane] = f2bu(val);
        }
      } else {
        if (i == 0){
          #pragma unroll
          for (int ii=0;ii<8;ii++){
            const int tt = (t0+8+ii) & (S_SEQ-1);
            xn[ii] = xbase[tt*D_DIM + lane];
          }
        }
        float xl = xr[i];
        float s0 = wb0*xl, s1 = wb1*xl, s2 = wb2*xl, s3 = wb3*xl;
        wave_sum4(s0,s1,s2,s3);
        float bb0 = __builtin_amdgcn_rcpf(1.f+__expf(-s0));
        float bb1 = __builtin_amdgcn_rcpf(1.f+__expf(-s1));
        float bb2 = __builtin_amdgcn_rcpf(1.f+__expf(-s2));
        b3_reg    = __builtin_amdgcn_rcpf(1.f+__expf(-s3));
        if (lane==0){
          beta_s[buf][0]=bb0; beta_s[buf][1]=bb1; beta_s[buf][2]=bb2;
          beta_s[buf][3]=b3_reg;
        }
      }
      lds_barrier();
      // ================ phase C ================
      if (wave < 3){
        { // prefetch next x row into SGPRs (hidden under phase C) [R18 pos]
          const int tn = (t+1) & (S_SEQ-1);
          sload_x64(xbase + tn*D_DIM, xc0, xc1, xc2, xc3);
        }
        float bw = beta_s[buf][wave];
        const uint4* qp = reinterpret_cast<const uint4*>(q_s[buf]);
        const uint4* kp = reinterpret_cast<const uint4*>(k_s[buf]);
        float kr[64];
        float a0=0.f,a1=0.f;
        #pragma unroll
        for (int j=0;j<8;j++){                  // 8 x uint4 = 64 bf16
          uint4 qv4 = qp[j];
          uint4 kv4 = kp[j];
          u32 qa[4] = {qv4.x,qv4.y,qv4.z,qv4.w};
          u32 ka[4] = {kv4.x,kv4.y,kv4.z,kv4.w};
          #pragma unroll
          for (int w=0;w<4;w++){
            float ql = __uint_as_float(qa[w]<<16);
            float qh = __uint_as_float(qa[w] & 0xffff0000u);
            float kl = __uint_as_float(ka[w]<<16);
            float kh = __uint_as_float(ka[w] & 0xffff0000u);
            const int e = j*8 + w*2;
            kr[e+0]=kl; kr[e+1]=kh;
            a0 = fmaf(W[e+0], ql-kl, a0);
            a1 = fmaf(W[e+1], qh-kh, a1);
          }
        }
        float rd = a0+a1;
        float cc = bw * rd;
        #pragma unroll
        for (int j=0;j<64;j++)
          W[j] = fmaf(cc, kr[j], W[j]);
      } else {
        float qn = __uint_as_float(((u32)q_s[buf][lane])<<16);
        float kn = __uint_as_float(((u32)k_s[buf][lane])<<16);
        float dv = qn - kn;
        float d0 = wb0*dv, d1 = wb1*dv, d2 = wb2*dv, d3 = wb3*dv;
        wave_sum4(d0,d1,d2,d3);
        float bk = b3_reg * kn;
        wb0 = fmaf(bk, d0, wb0);
        wb1 = fmaf(bk, d1, wb1);
        wb2 = fmaf(bk, d2, wb2);
        wb3 = fmaf(bk, d3, wb3);
      }
    }
    if (wave == 3){
      #pragma unroll
      for (int i=0;i<8;i++) xr[i] = xn[i];
    }
  }
#undef MV16

  if (wave < 3){
    const float* pp = (wave==0)? p_y : (wave==1)? p_q : p_k;
    float* o = ((wave==0)? o_sy : (wave==1)? o_sq : o_sk) + ((size_t)bh*64 + lane)*64;
    const float4* p4 = reinterpret_cast<const float4*>(pp + ((size_t)hh*64 + lane)*64);
    #pragma unroll
    for (int c=0;c<16;c++){
      float4 p = p4[c];
      float4 w;
      w.x = W[c*4+0]-p.x; w.y = W[c*4+1]-p.y; w.z = W[c*4+2]-p.z; w.w = W[c*4+3]-p.w;
      reinterpret_cast<float4*>(o)[c] = w;
    }
  } else {
    float4 pv = *reinterpret_cast<const float4*>(p_b + ((size_t)hh*64+lane)*4);
    float4 w;
    w.x = wb0-pv.x; w.y = wb1-pv.y; w.z = wb2-pv.z; w.w = wb3-pv.w;
    *reinterpret_cast<float4*>(o_sb + ((size_t)bh*64+lane)*4) = w;
  }
}

// ---------------------------------------------------------------------------
// bf16 MFMA GEMM, bf16 operands: C = A·B^T (+bias)(+Cin)(relu) -> f32 or bf16.
// Tile BMxBN (templated), BK=64, 4 waves (2x2 of BM/2 x BN/2), 16x16x32 MFMA.
// ---------------------------------------------------------------------------
template<int BM,int BN,bool BIAS,bool RELU,bool ADDC,bool OBF>
__global__ __launch_bounds__(256) void mgemm_k(
    const u16* __restrict__ A, const u16* __restrict__ Bw,
    const float* __restrict__ Cin, const float* __restrict__ bias,
    float* __restrict__ Of, u16* __restrict__ Ob,
    int M, int N, int K)
{
  constexpr int BK  = 64;
  constexpr int LDT = 72;                       // u16 row stride (144 B)
  constexpr int WM  = BM/2, WN = BN/2;
  constexpr int FI  = WM/16, FJ = WN/16;
  __shared__ __align__(16) u16 As[BM][LDT];
  __shared__ __align__(16) u16 Bs[BN][LDT];

  const int tid  = threadIdx.x;
  const int wv   = tid >> 6;
  const int lane = tid & 63;
  const int wr   = (wv >> 1) * WM;
  const int wc   = (wv & 1) * WN;
  const int lr   = lane & 15;
  const int lg   = lane >> 4;
  const int m0 = blockIdx.y * BM, n0 = blockIdx.x * BN;

  constexpr int TPRA = 256/BM, CHA = BK/TPRA;
  constexpr int TPRB = 256/BN, CHB = BK/TPRB;
  const int srA = tid / TPRA, skA = (tid % TPRA) * CHA;
  const int srB = tid / TPRB, skB = (tid % TPRB) * CHB;

  f32x4 acc[FI][FJ] = {};

  for (int kt = 0; kt < K; kt += BK){
    {
      const uint4* src = reinterpret_cast<const uint4*>(A + (size_t)(m0+srA)*K + kt + skA);
      uint4* dst = reinterpret_cast<uint4*>(&As[srA][skA]);
      #pragma unroll
      for (int c=0;c<CHA/8;c++) dst[c] = src[c];
    }
    {
      const uint4* src = reinterpret_cast<const uint4*>(Bw + (size_t)(n0+srB)*K + kt + skB);
      uint4* dst = reinterpret_cast<uint4*>(&Bs[srB][skB]);
      #pragma unroll
      for (int c=0;c<CHB/8;c++) dst[c] = src[c];
    }
    __syncthreads();

    #pragma unroll
    for (int half=0; half<2; ++half){
      bf16x8 af[FI], bfb[FJ];
      #pragma unroll
      for (int i=0;i<FI;i++)
        af[i]  = *reinterpret_cast<const bf16x8*>(&As[wr + i*16 + lr][half*32 + lg*8]);
      #pragma unroll
      for (int j=0;j<FJ;j++)
        bfb[j] = *reinterpret_cast<const bf16x8*>(&Bs[wc + j*16 + lr][half*32 + lg*8]);
      #pragma unroll
      for (int i=0;i<FI;i++)
        #pragma unroll
        for (int j=0;j<FJ;j++)
          acc[i][j] = __builtin_amdgcn_mfma_f32_16x16x32_bf16(af[i], bfb[j], acc[i][j], 0,0,0);
    }
    __syncthreads();
  }

  // epilogue: D mapping col=lane&15, row=(lane>>4)*4+dj  [m89-verified]
  #pragma unroll
  for (int j=0;j<FJ;j++){
    const int col = n0 + wc + j*16 + lr;
    float bv = 0.f;
    if (BIAS) bv = bias[col];
    #pragma unroll
    for (int i=0;i<FI;i++){
      const int rbase = m0 + wr + i*16 + lg*4;
      #pragma unroll
      for (int dj=0;dj<4;dj++){
        const int row = rbase + dj;
        float v = acc[i][j][dj];
        if (BIAS) v += bv;
        if (ADDC) v += Cin[(size_t)row*N + col];
        if (RELU) v = fmaxf(v, 0.f);
        if (OBF) Ob[(size_t)row*N + col] = f2bu(v);
        else     Of[(size_t)row*N + col] = v;
      }
    }
  }
}

// ---------------------------------------------------------------------------
// LayerNorm over HID=512, wave per row, 8 elems/lane. f32 -> bf16.
// ---------------------------------------------------------------------------
__global__ __launch_bounds__(256) void ln_k(
    const float* __restrict__ h, const float* __restrict__ g,
    const float* __restrict__ bb, u16* __restrict__ out)
{
  int row  = blockIdx.x*4 + (threadIdx.x>>6);
  int lane = threadIdx.x & 63;
  const float4* hr = reinterpret_cast<const float4*>(h + (size_t)row*HID_D) + lane*2;
  float4 u = hr[0], v = hr[1];
  float vals[8] = {u.x,u.y,u.z,u.w,v.x,v.y,v.z,v.w};
  float s = 0.f;
  #pragma unroll
  for (int e=0;e<8;e++) s += vals[e];
  s = wave_sum(s);
  float mu = s * (1.f/HID_D);
  float vs = 0.f;
  #pragma unroll
  for (int e=0;e<8;e++){ float d = vals[e]-mu; vs += d*d; }
  vs = wave_sum(vs);
  float rs = rsqrtf(vs*(1.f/HID_D) + 1e-5f);
  const float4* gr = reinterpret_cast<const float4*>(g) + lane*2;
  const float4* br = reinterpret_cast<const float4*>(bb) + lane*2;
  float4 g0 = gr[0], g1 = gr[1], b0 = br[0], b1 = br[1];
  u16 ov[8];
  ov[0] = f2bu((vals[0]-mu)*rs*g0.x + b0.x);
  ov[1] = f2bu((vals[1]-mu)*rs*g0.y + b0.y);
  ov[2] = f2bu((vals[2]-mu)*rs*g0.z + b0.z);
  ov[3] = f2bu((vals[3]-mu)*rs*g0.w + b0.w);
  ov[4] = f2bu((vals[4]-mu)*rs*g1.x + b1.x);
  ov[5] = f2bu((vals[5]-mu)*rs*g1.y + b1.y);
  ov[6] = f2bu((vals[6]-mu)*rs*g1.z + b1.z);
  ov[7] = f2bu((vals[7]-mu)*rs*g1.w + b1.w);
  *reinterpret_cast<uint4*>(out + (size_t)row*HID_D + lane*8) =
      *reinterpret_cast<uint4*>(ov);
}

// ---------------------------------------------------------------------------
extern "C" void kernel_launch(void* const* d_in, const int* in_sizes, int n_in,
                              void* d_out, int out_size, void* d_ws, size_t ws_size,
                              hipStream_t stream)
{
  const float* x    = (const float*)d_in[0];
  const float* sty  = (const float*)d_in[1];
  const float* stq  = (const float*)d_in[2];
  const float* stk  = (const float*)d_in[3];
  const float* stb  = (const float*)d_in[4];
  const float* inW  = (const float*)d_in[5];
  const float* inb  = (const float*)d_in[6];
  const float* py   = (const float*)d_in[7];
  const float* pq   = (const float*)d_in[8];
  const float* pk   = (const float*)d_in[9];
  const float* pb   = (const float*)d_in[10];
  const float* Wo   = (const float*)d_in[11];
  const float* fw1  = (const float*)d_in[12];
  const float* fb1  = (const float*)d_in[13];
  const float* fw2  = (const float*)d_in[14];
  const float* fb2  = (const float*)d_in[15];
  const float* lng  = (const float*)d_in[16];
  const float* lnb  = (const float*)d_in[17];

  char* ws = (char*)d_ws;
  float* h    = (float*)ws;                          // 0..4 MB
  float* xsb  = (float*)(ws + (4<<20));              // 4..8 MB
  u16*   yb   = (u16*)  (ws + (8<<20));              // 8..10 MB (bf16 y)
  u16*   t0   = (u16*)  (ws + (10<<20));             // 10..12 MB (bf16 ln out)
  u16*   t1   = (u16*)  (ws + (12<<20));             // 12..20 MB (bf16 ff mid)
  u16*   xb   = (u16*)  (ws + (20<<20));             // 20..22 MB
  u16*   inWb = (u16*)  (ws + (22<<20));             // 0.5 MB
  u16*   Wob  = (u16*)  (ws + (22<<20) + (512*1024));// 1 MB
  u16*   fw1b = (u16*)  (ws + (23<<20) + (512*1024));// 4 MB
  u16*   fw2b = (u16*)  (ws + (27<<20) + (512*1024));// 4 MB (ends 31.5 MB)

  float* out0 = (float*)d_out;
  const size_t OUT_SZ = (size_t)S_SEQ*B_NUM*HID_D;          // 1048576
  const size_t SYL    = (size_t)B_NUM*H_NUM*D_DIM*D_DIM;    // 262144 per layer
  const size_t SBL    = (size_t)B_NUM*H_NUM*D_DIM*4;        // 16384  per layer
  float* o_sy = out0 + OUT_SZ;
  float* o_sq = o_sy + L_NUM*SYL;
  float* o_sk = o_sq + L_NUM*SYL;
  float* o_sb = o_sk + L_NUM*SYL;

  const int M = S_SEQ*B_NUM;   // 2048

  // one-time bf16 conversions (graph-capture safe, deterministic)
  cvt_bf16_k<<<512, 256,0,stream>>>(x,   xb,   M*512/8);
  cvt_bf16_k<<<128, 256,0,stream>>>(inW, inWb, 512*512/8);
  cvt_bf16_k<<<256, 256,0,stream>>>(Wo,  Wob,  L_NUM*512*512/8);
  cvt_bf16_k<<<1024,256,0,stream>>>(fw1, fw1b, L_NUM*FF_D*HID_D/8);
  cvt_bf16_k<<<1024,256,0,stream>>>(fw2, fw2b, L_NUM*HID_D*FF_D/8);

  // in-projection: h = x @ in_W.T + in_b   (64x64 tile -> 256 blocks)
  mgemm_k<64,64,true,false,false,false><<<dim3(HID_D/64, M/64),256,0,stream>>>(
      xb, inWb, nullptr, inb, h, nullptr, M, HID_D, 512);

  for (int l=0;l<L_NUM;l++){
    softmax_xs_k<<<(S_SEQ*B_NUM*H_NUM)/4, 256, 0, stream>>>(h, xsb);

    scan4_k<<<B_NUM*H_NUM, 256, 0, stream>>>(xsb,
        sty + (size_t)l*SYL, stq + (size_t)l*SYL, stk + (size_t)l*SYL, stb + (size_t)l*SBL,
        py + (size_t)l*H_NUM*D_DIM*D_DIM, pq + (size_t)l*H_NUM*D_DIM*D_DIM,
        pk + (size_t)l*H_NUM*D_DIM*D_DIM, pb + (size_t)l*H_NUM*D_DIM*4,
        yb,
        o_sy + l*SYL, o_sq + l*SYL, o_sk + l*SYL, o_sb + l*SBL);

    // h += y @ Wo.T   (64x64 tile -> 256 blocks)
    mgemm_k<64,64,false,false,true,false><<<dim3(HID_D/64, M/64),256,0,stream>>>(
        yb, Wob + (size_t)l*HID_D*HID_D, h, nullptr, h, nullptr, M, HID_D, HID_D);

    ln_k<<<M/4,256,0,stream>>>(h, lng + l*HID_D, lnb + l*HID_D, t0);

    // t1 = relu(ln @ ff_W1.T + b1)  -> bf16  (128x128 tile, 256 blocks)
    mgemm_k<128,128,true,true,false,true><<<dim3(FF_D/128, M/128),256,0,stream>>>(
        t0, fw1b + (size_t)l*FF_D*HID_D, nullptr, fb1 + l*FF_D, nullptr, t1, M, FF_D, HID_D);

    // h(+out) = h + t1 @ ff_W2.T + b2   (64x64 tile -> 256 blocks)
    float* dst = (l==L_NUM-1) ? out0 : h;
    mgemm_k<64,64,true,false,true,false><<<dim3(HID_D/64, M/64),256,0,stream>>>(
        t1, fw2b + (size_t)l*HID_D*FF_D, h, fb2 + l*HID_D, dst, nullptr, M, HID_D, FF_D);
  }
}

// Round 23
// 639.655 us; speedup vs baseline: 1.6626x; 1.0036x over previous
//
#include <hip/hip_runtime.h>

#define L_NUM 2
#define H_NUM 8
#define D_DIM 64
#define HID_D 512
#define FF_D  2048
#define S_SEQ 256
#define B_NUM 8

typedef unsigned short u16;
typedef unsigned int   u32;
typedef __attribute__((ext_vector_type(8))) short bf16x8;
typedef __attribute__((ext_vector_type(4))) float f32x4;
typedef __attribute__((ext_vector_type(16))) int i32x16;

__device__ __forceinline__ u16 f2bu(float f){
  u32 u = __float_as_uint(f);
  u32 r = (u + 0x7fffu + ((u>>16)&1u)) >> 16;   // RNE to bf16
  return (u16)r;
}

template<int CTL,int RM,int BM>
__device__ __forceinline__ float dpp_add_src(float v){
  return __int_as_float(__builtin_amdgcn_update_dpp(0, __float_as_int(v), CTL, RM, BM, false));
}

__device__ __forceinline__ float rlane(float v, int l){
  return __int_as_float(__builtin_amdgcn_readlane(__float_as_int(v), l));
}

// ---------------------------------------------------------------------------
// Wave64 sum, shallow: 4 DPP row_shr levels (exact row sums land in lanes
// 15/31/47/63; 0-identity fill) + 4 parallel readlanes + 3 adds. Exact.
// ---------------------------------------------------------------------------
__device__ __forceinline__ float wave_sum(float v){
  float t;
  t = dpp_add_src<0x111,0xf,0xf>(v); v += t;
  t = dpp_add_src<0x112,0xf,0xf>(v); v += t;
  t = dpp_add_src<0x114,0xf,0xf>(v); v += t;
  t = dpp_add_src<0x118,0xf,0xf>(v); v += t;
  return (rlane(v,15)+rlane(v,31))+(rlane(v,47)+rlane(v,63));
}

// 4 interleaved sums (independent chains share the 4 DPP levels).
__device__ __forceinline__ void wave_sum4(float&a,float&b,float&c,float&d){
  float ta,tb,tc,td;
  ta=dpp_add_src<0x111,0xf,0xf>(a); tb=dpp_add_src<0x111,0xf,0xf>(b);
  tc=dpp_add_src<0x111,0xf,0xf>(c); td=dpp_add_src<0x111,0xf,0xf>(d);
  a+=ta; b+=tb; c+=tc; d+=td;
  ta=dpp_add_src<0x112,0xf,0xf>(a); tb=dpp_add_src<0x112,0xf,0xf>(b);
  tc=dpp_add_src<0x112,0xf,0xf>(c); td=dpp_add_src<0x112,0xf,0xf>(d);
  a+=ta; b+=tb; c+=tc; d+=td;
  ta=dpp_add_src<0x114,0xf,0xf>(a); tb=dpp_add_src<0x114,0xf,0xf>(b);
  tc=dpp_add_src<0x114,0xf,0xf>(c); td=dpp_add_src<0x114,0xf,0xf>(d);
  a+=ta; b+=tb; c+=tc; d+=td;
  ta=dpp_add_src<0x118,0xf,0xf>(a); tb=dpp_add_src<0x118,0xf,0xf>(b);
  tc=dpp_add_src<0x118,0xf,0xf>(c); td=dpp_add_src<0x118,0xf,0xf>(d);
  a+=ta; b+=tb; c+=tc; d+=td;
  a = (rlane(a,15)+rlane(a,31))+(rlane(a,47)+rlane(a,63));
  b = (rlane(b,15)+rlane(b,31))+(rlane(b,47)+rlane(b,63));
  c = (rlane(c,15)+rlane(c,31))+(rlane(c,47)+rlane(c,63));
  d = (rlane(d,15)+rlane(d,31))+(rlane(d,47)+rlane(d,63));
}

// LDS-only barrier: does NOT drain vmcnt (global ops stay in flight).
__device__ __forceinline__ void lds_barrier(){
  __builtin_amdgcn_sched_barrier(0);
  asm volatile("s_waitcnt lgkmcnt(0)" ::: "memory");
  __builtin_amdgcn_s_barrier();
  __builtin_amdgcn_sched_barrier(0);
}

// Uniform 64-float row -> 64 SGPRs (4x s_load_dwordx16). Pointer MUST be
// provably uniform. Only safe for data produced by a PRIOR kernel.
// POSITION-SENSITIVE: must be issued at the START of phase C (R18/R21
// position). Both repositioning attempts (R19 tail+fences, R22 plain tail)
// produced crashes/NaN — hipcc's waitcnt bookkeeping around this asm block
// is only correct where the q/k ds_read waits conservatively drain it.
__device__ __forceinline__ void sload_x64(const float* p,
    i32x16& a, i32x16& b, i32x16& c, i32x16& d){
  asm volatile(
    "s_load_dwordx16 %0, %4, 0x0\n\t"
    "s_load_dwordx16 %1, %4, 0x40\n\t"
    "s_load_dwordx16 %2, %4, 0x80\n\t"
    "s_load_dwordx16 %3, %4, 0xC0"
    : "=&s"(a), "=&s"(b), "=&s"(c), "=&s"(d)
    : "s"((unsigned long long)(__SIZE_TYPE__)p));
}

// ---------------------------------------------------------------------------
// f32 -> bf16 convert, 8 elems/thread.
// ---------------------------------------------------------------------------
__global__ __launch_bounds__(256) void cvt_bf16_k(
    const float* __restrict__ in, u16* __restrict__ out, int n8)
{
  int i = blockIdx.x*256 + threadIdx.x;
  if (i < n8){
    const float4* p = reinterpret_cast<const float4*>(in + (size_t)i*8);
    float4 v0 = p[0], v1 = p[1];
    u16 t[8] = {f2bu(v0.x),f2bu(v0.y),f2bu(v0.z),f2bu(v0.w),
                f2bu(v1.x),f2bu(v1.y),f2bu(v1.z),f2bu(v1.w)};
    *reinterpret_cast<uint4*>(out + (size_t)i*8) = *reinterpret_cast<uint4*>(t);
  }
}

// ---------------------------------------------------------------------------
// Per-head softmax: h (S,B,HID) f32 -> xs (B,H,S,D) f32. One wave per 64-row.
// ---------------------------------------------------------------------------
__global__ __launch_bounds__(256) void softmax_xs_k(
    const float* __restrict__ h, float* __restrict__ xs)
{
  int rid  = blockIdx.x*4 + (threadIdx.x>>6);   // (s*B+b)*H + hd
  int lane = threadIdx.x & 63;
  int hd = rid & (H_NUM-1);
  int sb = rid >> 3;                            // s*B + b
  int b  = sb & (B_NUM-1);
  int s  = sb >> 3;
  float v = h[(size_t)sb*HID_D + hd*D_DIM + lane];
  float m = v;
  #pragma unroll
  for (int off=32; off; off>>=1) m = fmaxf(m, __shfl_xor(m, off));
  float e = __expf(v-m);
  float sum = wave_sum(e);
  xs[(((size_t)(b*H_NUM+hd))*S_SEQ + s)*D_DIM + lane] = e/sum;
}

// ---------------------------------------------------------------------------
// SRWM scan, 4 waves per (b,h). x via SGPR s_loads (prior-kernel data -> K$
// safe). q/k stored as bf16 in LDS (halves phase-C broadcast LDS traffic).
// sload prefetch at START of phase C (verified position). R21: 244 us.
// ---------------------------------------------------------------------------
__global__ __launch_bounds__(256,1) void scan4_k(
    const float* __restrict__ xs,
    const float* __restrict__ st_y, const float* __restrict__ st_q,
    const float* __restrict__ st_k, const float* __restrict__ st_b,
    const float* __restrict__ p_y,  const float* __restrict__ p_q,
    const float* __restrict__ p_k,  const float* __restrict__ p_b,
    u16* __restrict__ y_out,                    // (S,B,HID) bf16
    float* __restrict__ o_sy, float* __restrict__ o_sq,
    float* __restrict__ o_sk, float* __restrict__ o_sb)
{
  const int bh = blockIdx.x;
  const int b  = bh >> 3, hh = bh & 7;
  const int wave = threadIdx.x >> 6, lane = threadIdx.x & 63;

  __shared__ __align__(16) u16 q_s[2][64];      // bf16 q
  __shared__ __align__(16) u16 k_s[2][64];      // bf16 k
  __shared__ float beta_s[2][4];

  float W[64];
  float wb0=0.f, wb1=0.f, wb2=0.f, wb3=0.f;
  float xr[8], xn[8];
  float b3_reg=0.f;
  i32x16 xc0, xc1, xc2, xc3;                    // wave<3: x row in SGPRs

  const float* xbase = xs + (size_t)bh * (S_SEQ*D_DIM);

  if (wave < 3) {
    const float* st = (wave==0)? st_y : (wave==1)? st_q : st_k;
    const float* pp = (wave==0)? p_y  : (wave==1)? p_q  : p_k;
    const float4* s4 = reinterpret_cast<const float4*>(st + ((size_t)bh*64 + lane)*64);
    const float4* p4 = reinterpret_cast<const float4*>(pp + ((size_t)hh*64 + lane)*64);
    #pragma unroll
    for (int c=0;c<16;c++){
      float4 a = s4[c], p = p4[c];
      W[c*4+0]=a.x+p.x; W[c*4+1]=a.y+p.y; W[c*4+2]=a.z+p.z; W[c*4+3]=a.w+p.w;
    }
    sload_x64(xbase, xc0, xc1, xc2, xc3);       // x row for t=0
  } else {
    float4 sv = *reinterpret_cast<const float4*>(st_b + ((size_t)bh*64+lane)*4);
    float4 pv = *reinterpret_cast<const float4*>(p_b  + ((size_t)hh*64+lane)*4);
    wb0 = sv.x+pv.x; wb1 = sv.y+pv.y; wb2 = sv.z+pv.z; wb3 = sv.w+pv.w;
    #pragma unroll
    for (int i=0;i<8;i++) xr[i] = xbase[i*D_DIM + lane];
  }
  __syncthreads();

#define MV16(XV, BASE)                                              \
    _Pragma("unroll")                                               \
    for (int e=0;e<16;e+=4){                                        \
      a0 = fmaf(W[(BASE)+e+0], __int_as_float(XV[e+0]), a0);        \
      a1 = fmaf(W[(BASE)+e+1], __int_as_float(XV[e+1]), a1);        \
      a2 = fmaf(W[(BASE)+e+2], __int_as_float(XV[e+2]), a2);        \
      a3 = fmaf(W[(BASE)+e+3], __int_as_float(XV[e+3]), a3);        \
    }

  for (int t0=0; t0<S_SEQ; t0+=8){
    #pragma unroll
    for (int i=0;i<8;i++){
      const int t = t0 + i;
      const int buf = i & 1;
      // ================ phase A ================
      if (wave < 3){
        asm volatile("s_waitcnt lgkmcnt(0)" ::: "memory");  // s_load done
        float a0=0.f,a1=0.f,a2=0.f,a3=0.f;
        MV16(xc0, 0)
        MV16(xc1, 16)
        MV16(xc2, 32)
        MV16(xc3, 48)
        float r = (a0+a1)+(a2+a3);
        if (wave==0){
          y_out[((size_t)t*B_NUM + b)*HID_D + hh*D_DIM + lane] = f2bu(r);
        } else {
          float e = __expf(r);
          float s = wave_sum(e);
          float val = e * __builtin_amdgcn_rcpf(s);
          (wave==1 ? q_s[buf] : k_s[buf])[lane] = f2bu(val);
        }
      } else {
        if (i == 0){
          #pragma unroll
          for (int ii=0;ii<8;ii++){
            const int tt = (t0+8+ii) & (S_SEQ-1);
            xn[ii] = xbase[tt*D_DIM + lane];
          }
        }
        float xl = xr[i];
        float s0 = wb0*xl, s1 = wb1*xl, s2 = wb2*xl, s3 = wb3*xl;
        wave_sum4(s0,s1,s2,s3);
        float bb0 = __builtin_amdgcn_rcpf(1.f+__expf(-s0));
        float bb1 = __builtin_amdgcn_rcpf(1.f+__expf(-s1));
        float bb2 = __builtin_amdgcn_rcpf(1.f+__expf(-s2));
        b3_reg    = __builtin_amdgcn_rcpf(1.f+__expf(-s3));
        if (lane==0){
          beta_s[buf][0]=bb0; beta_s[buf][1]=bb1; beta_s[buf][2]=bb2;
          beta_s[buf][3]=b3_reg;
        }
      }
      lds_barrier();
      // ================ phase C ================
      if (wave < 3){
        { // prefetch next x row into SGPRs (verified R18/R21 position)
          const int tn = (t+1) & (S_SEQ-1);
          sload_x64(xbase + tn*D_DIM, xc0, xc1, xc2, xc3);
        }
        float bw = beta_s[buf][wave];
        const uint4* qp = reinterpret_cast<const uint4*>(q_s[buf]);
        const uint4* kp = reinterpret_cast<const uint4*>(k_s[buf]);
        float kr[64];
        float a0=0.f,a1=0.f;
        #pragma unroll
        for (int j=0;j<8;j++){                  // 8 x uint4 = 64 bf16
          uint4 qv4 = qp[j];
          uint4 kv4 = kp[j];
          u32 qa[4] = {qv4.x,qv4.y,qv4.z,qv4.w};
          u32 ka[4] = {kv4.x,kv4.y,kv4.z,kv4.w};
          #pragma unroll
          for (int w=0;w<4;w++){
            float ql = __uint_as_float(qa[w]<<16);
            float qh = __uint_as_float(qa[w] & 0xffff0000u);
            float kl = __uint_as_float(ka[w]<<16);
            float kh = __uint_as_float(ka[w] & 0xffff0000u);
            const int e = j*8 + w*2;
            kr[e+0]=kl; kr[e+1]=kh;
            a0 = fmaf(W[e+0], ql-kl, a0);
            a1 = fmaf(W[e+1], qh-kh, a1);
          }
        }
        float rd = a0+a1;
        float cc = bw * rd;
        #pragma unroll
        for (int j=0;j<64;j++)
          W[j] = fmaf(cc, kr[j], W[j]);
      } else {
        float qn = __uint_as_float(((u32)q_s[buf][lane])<<16);
        float kn = __uint_as_float(((u32)k_s[buf][lane])<<16);
        float dv = qn - kn;
        float d0 = wb0*dv, d1 = wb1*dv, d2 = wb2*dv, d3 = wb3*dv;
        wave_sum4(d0,d1,d2,d3);
        float bk = b3_reg * kn;
        wb0 = fmaf(bk, d0, wb0);
        wb1 = fmaf(bk, d1, wb1);
        wb2 = fmaf(bk, d2, wb2);
        wb3 = fmaf(bk, d3, wb3);
      }
    }
    if (wave == 3){
      #pragma unroll
      for (int i=0;i<8;i++) xr[i] = xn[i];
    }
  }
#undef MV16

  if (wave < 3){
    const float* pp = (wave==0)? p_y : (wave==1)? p_q : p_k;
    float* o = ((wave==0)? o_sy : (wave==1)? o_sq : o_sk) + ((size_t)bh*64 + lane)*64;
    const float4* p4 = reinterpret_cast<const float4*>(pp + ((size_t)hh*64 + lane)*64);
    #pragma unroll
    for (int c=0;c<16;c++){
      float4 p = p4[c];
      float4 w;
      w.x = W[c*4+0]-p.x; w.y = W[c*4+1]-p.y; w.z = W[c*4+2]-p.z; w.w = W[c*4+3]-p.w;
      reinterpret_cast<float4*>(o)[c] = w;
    }
  } else {
    float4 pv = *reinterpret_cast<const float4*>(p_b + ((size_t)hh*64+lane)*4);
    float4 w;
    w.x = wb0-pv.x; w.y = wb1-pv.y; w.z = wb2-pv.z; w.w = wb3-pv.w;
    *reinterpret_cast<float4*>(o_sb + ((size_t)bh*64+lane)*4) = w;
  }
}

// ---------------------------------------------------------------------------
// bf16 MFMA GEMM, bf16 operands: C = A·B^T (+bias)(+Cin)(relu) -> f32 or bf16.
// Tile BMxBN (templated), BK=64, 4 waves (2x2 of BM/2 x BN/2), 16x16x32 MFMA.
// ---------------------------------------------------------------------------
template<int BM,int BN,bool BIAS,bool RELU,bool ADDC,bool OBF>
__global__ __launch_bounds__(256) void mgemm_k(
    const u16* __restrict__ A, const u16* __restrict__ Bw,
    const float* __restrict__ Cin, const float* __restrict__ bias,
    float* __restrict__ Of, u16* __restrict__ Ob,
    int M, int N, int K)
{
  constexpr int BK  = 64;
  constexpr int LDT = 72;                       // u16 row stride (144 B)
  constexpr int WM  = BM/2, WN = BN/2;
  constexpr int FI  = WM/16, FJ = WN/16;
  __shared__ __align__(16) u16 As[BM][LDT];
  __shared__ __align__(16) u16 Bs[BN][LDT];

  const int tid  = threadIdx.x;
  const int wv   = tid >> 6;
  const int lane = tid & 63;
  const int wr   = (wv >> 1) * WM;
  const int wc   = (wv & 1) * WN;
  const int lr   = lane & 15;
  const int lg   = lane >> 4;
  const int m0 = blockIdx.y * BM, n0 = blockIdx.x * BN;

  constexpr int TPRA = 256/BM, CHA = BK/TPRA;
  constexpr int TPRB = 256/BN, CHB = BK/TPRB;
  const int srA = tid / TPRA, skA = (tid % TPRA) * CHA;
  const int srB = tid / TPRB, skB = (tid % TPRB) * CHB;

  f32x4 acc[FI][FJ] = {};

  for (int kt = 0; kt < K; kt += BK){
    {
      const uint4* src = reinterpret_cast<const uint4*>(A + (size_t)(m0+srA)*K + kt + skA);
      uint4* dst = reinterpret_cast<uint4*>(&As[srA][skA]);
      #pragma unroll
      for (int c=0;c<CHA/8;c++) dst[c] = src[c];
    }
    {
      const uint4* src = reinterpret_cast<const uint4*>(Bw + (size_t)(n0+srB)*K + kt + skB);
      uint4* dst = reinterpret_cast<uint4*>(&Bs[srB][skB]);
      #pragma unroll
      for (int c=0;c<CHB/8;c++) dst[c] = src[c];
    }
    __syncthreads();

    #pragma unroll
    for (int half=0; half<2; ++half){
      bf16x8 af[FI], bfb[FJ];
      #pragma unroll
      for (int i=0;i<FI;i++)
        af[i]  = *reinterpret_cast<const bf16x8*>(&As[wr + i*16 + lr][half*32 + lg*8]);
      #pragma unroll
      for (int j=0;j<FJ;j++)
        bfb[j] = *reinterpret_cast<const bf16x8*>(&Bs[wc + j*16 + lr][half*32 + lg*8]);
      #pragma unroll
      for (int i=0;i<FI;i++)
        #pragma unroll
        for (int j=0;j<FJ;j++)
          acc[i][j] = __builtin_amdgcn_mfma_f32_16x16x32_bf16(af[i], bfb[j], acc[i][j], 0,0,0);
    }
    __syncthreads();
  }

  // epilogue: D mapping col=lane&15, row=(lane>>4)*4+dj  [m89-verified]
  #pragma unroll
  for (int j=0;j<FJ;j++){
    const int col = n0 + wc + j*16 + lr;
    float bv = 0.f;
    if (BIAS) bv = bias[col];
    #pragma unroll
    for (int i=0;i<FI;i++){
      const int rbase = m0 + wr + i*16 + lg*4;
      #pragma unroll
      for (int dj=0;dj<4;dj++){
        const int row = rbase + dj;
        float v = acc[i][j][dj];
        if (BIAS) v += bv;
        if (ADDC) v += Cin[(size_t)row*N + col];
        if (RELU) v = fmaxf(v, 0.f);
        if (OBF) Ob[(size_t)row*N + col] = f2bu(v);
        else     Of[(size_t)row*N + col] = v;
      }
    }
  }
}

// ---------------------------------------------------------------------------
// LayerNorm over HID=512, wave per row, 8 elems/lane. f32 -> bf16.
// ---------------------------------------------------------------------------
__global__ __launch_bounds__(256) void ln_k(
    const float* __restrict__ h, const float* __restrict__ g,
    const float* __restrict__ bb, u16* __restrict__ out)
{
  int row  = blockIdx.x*4 + (threadIdx.x>>6);
  int lane = threadIdx.x & 63;
  const float4* hr = reinterpret_cast<const float4*>(h + (size_t)row*HID_D) + lane*2;
  float4 u = hr[0], v = hr[1];
  float vals[8] = {u.x,u.y,u.z,u.w,v.x,v.y,v.z,v.w};
  float s = 0.f;
  #pragma unroll
  for (int e=0;e<8;e++) s += vals[e];
  s = wave_sum(s);
  float mu = s * (1.f/HID_D);
  float vs = 0.f;
  #pragma unroll
  for (int e=0;e<8;e++){ float d = vals[e]-mu; vs += d*d; }
  vs = wave_sum(vs);
  float rs = rsqrtf(vs*(1.f/HID_D) + 1e-5f);
  const float4* gr = reinterpret_cast<const float4*>(g) + lane*2;
  const float4* br = reinterpret_cast<const float4*>(bb) + lane*2;
  float4 g0 = gr[0], g1 = gr[1], b0 = br[0], b1 = br[1];
  u16 ov[8];
  ov[0] = f2bu((vals[0]-mu)*rs*g0.x + b0.x);
  ov[1] = f2bu((vals[1]-mu)*rs*g0.y + b0.y);
  ov[2] = f2bu((vals[2]-mu)*rs*g0.z + b0.z);
  ov[3] = f2bu((vals[3]-mu)*rs*g0.w + b0.w);
  ov[4] = f2bu((vals[4]-mu)*rs*g1.x + b1.x);
  ov[5] = f2bu((vals[5]-mu)*rs*g1.y + b1.y);
  ov[6] = f2bu((vals[6]-mu)*rs*g1.z + b1.z);
  ov[7] = f2bu((vals[7]-mu)*rs*g1.w + b1.w);
  *reinterpret_cast<uint4*>(out + (size_t)row*HID_D + lane*8) =
      *reinterpret_cast<uint4*>(ov);
}

// ---------------------------------------------------------------------------
extern "C" void kernel_launch(void* const* d_in, const int* in_sizes, int n_in,
                              void* d_out, int out_size, void* d_ws, size_t ws_size,
                              hipStream_t stream)
{
  const float* x    = (const float*)d_in[0];
  const float* sty  = (const float*)d_in[1];
  const float* stq  = (const float*)d_in[2];
  const float* stk  = (const float*)d_in[3];
  const float* stb  = (const float*)d_in[4];
  const float* inW  = (const float*)d_in[5];
  const float* inb  = (const float*)d_in[6];
  const float* py   = (const float*)d_in[7];
  const float* pq   = (const float*)d_in[8];
  const float* pk   = (const float*)d_in[9];
  const float* pb   = (const float*)d_in[10];
  const float* Wo   = (const float*)d_in[11];
  const float* fw1  = (const float*)d_in[12];
  const float* fb1  = (const float*)d_in[13];
  const float* fw2  = (const float*)d_in[14];
  const float* fb2  = (const float*)d_in[15];
  const float* lng  = (const float*)d_in[16];
  const float* lnb  = (const float*)d_in[17];

  char* ws = (char*)d_ws;
  float* h    = (float*)ws;                          // 0..4 MB
  float* xsb  = (float*)(ws + (4<<20));              // 4..8 MB
  u16*   yb   = (u16*)  (ws + (8<<20));              // 8..10 MB (bf16 y)
  u16*   t0   = (u16*)  (ws + (10<<20));             // 10..12 MB (bf16 ln out)
  u16*   t1   = (u16*)  (ws + (12<<20));             // 12..20 MB (bf16 ff mid)
  u16*   xb   = (u16*)  (ws + (20<<20));             // 20..22 MB
  u16*   inWb = (u16*)  (ws + (22<<20));             // 0.5 MB
  u16*   Wob  = (u16*)  (ws + (22<<20) + (512*1024));// 1 MB
  u16*   fw1b = (u16*)  (ws + (23<<20) + (512*1024));// 4 MB
  u16*   fw2b = (u16*)  (ws + (27<<20) + (512*1024));// 4 MB (ends 31.5 MB)

  float* out0 = (float*)d_out;
  const size_t OUT_SZ = (size_t)S_SEQ*B_NUM*HID_D;          // 1048576
  const size_t SYL    = (size_t)B_NUM*H_NUM*D_DIM*D_DIM;    // 262144 per layer
  const size_t SBL    = (size_t)B_NUM*H_NUM*D_DIM*4;        // 16384  per layer
  float* o_sy = out0 + OUT_SZ;
  float* o_sq = o_sy + L_NUM*SYL;
  float* o_sk = o_sq + L_NUM*SYL;
  float* o_sb = o_sk + L_NUM*SYL;

  const int M = S_SEQ*B_NUM;   // 2048

  // one-time bf16 conversions (graph-capture safe, deterministic)
  cvt_bf16_k<<<512, 256,0,stream>>>(x,   xb,   M*512/8);
  cvt_bf16_k<<<128, 256,0,stream>>>(inW, inWb, 512*512/8);
  cvt_bf16_k<<<256, 256,0,stream>>>(Wo,  Wob,  L_NUM*512*512/8);
  cvt_bf16_k<<<1024,256,0,stream>>>(fw1, fw1b, L_NUM*FF_D*HID_D/8);
  cvt_bf16_k<<<1024,256,0,stream>>>(fw2, fw2b, L_NUM*HID_D*FF_D/8);

  // in-projection: h = x @ in_W.T + in_b   (64x64 tile -> 256 blocks)
  mgemm_k<64,64,true,false,false,false><<<dim3(HID_D/64, M/64),256,0,stream>>>(
      xb, inWb, nullptr, inb, h, nullptr, M, HID_D, 512);

  for (int l=0;l<L_NUM;l++){
    softmax_xs_k<<<(S_SEQ*B_NUM*H_NUM)/4, 256, 0, stream>>>(h, xsb);

    scan4_k<<<B_NUM*H_NUM, 256, 0, stream>>>(xsb,
        sty + (size_t)l*SYL, stq + (size_t)l*SYL, stk + (size_t)l*SYL, stb + (size_t)l*SBL,
        py + (size_t)l*H_NUM*D_DIM*D_DIM, pq + (size_t)l*H_NUM*D_DIM*D_DIM,
        pk + (size_t)l*H_NUM*D_DIM*D_DIM, pb + (size_t)l*H_NUM*D_DIM*4,
        yb,
        o_sy + l*SYL, o_sq + l*SYL, o_sk + l*SYL, o_sb + l*SBL);

    // h += y @ Wo.T   (64x64 tile -> 256 blocks)
    mgemm_k<64,64,false,false,true,false><<<dim3(HID_D/64, M/64),256,0,stream>>>(
        yb, Wob + (size_t)l*HID_D*HID_D, h, nullptr, h, nullptr, M, HID_D, HID_D);

    ln_k<<<M/4,256,0,stream>>>(h, lng + l*HID_D, lnb + l*HID_D, t0);

    // t1 = relu(ln @ ff_W1.T + b1)  -> bf16  (128x128 tile, 256 blocks)
    mgemm_k<128,128,true,true,false,true><<<dim3(FF_D/128, M/128),256,0,stream>>>(
        t0, fw1b + (size_t)l*FF_D*HID_D, nullptr, fb1 + l*FF_D, nullptr, t1, M, FF_D, HID_D);

    // h(+out) = h + t1 @ ff_W2.T + b2   (64x64 tile -> 256 blocks)
    float* dst = (l==L_NUM-1) ? out0 : h;
    mgemm_k<64,64,true,false,true,false><<<dim3(HID_D/64, M/64),256,0,stream>>>(
        t1, fw2b + (size_t)l*HID_D*FF_D, h, fb2 + l*HID_D, dst, nullptr, M, HID_D, FF_D);
  }
}